// Round 1
// baseline (4985.769 us; speedup 1.0000x reference)
//
#include <hip/hip_runtime.h>
#include <math.h>

#define IH 48
#define IW 48
#define LTOT 2304      // 48*48
#define CS 128
#define HS 96
#define KRED 1152      // 3*3*128
#define CRED 2048      // 4*4*128

#define NXP ((size_t)LTOT*KRED)
#define NW  ((size_t)LTOT*KRED)
#define NS  ((size_t)LTOT*LTOT)
#define NR  ((size_t)LTOT*CRED)
#define NC  ((size_t)LTOT*CRED)
#define NMM ((size_t)LTOT)

// ---------------- gathers ----------------
// Xp[p*1152 + G], G=(k1*384 + k2*128 + c): fd_pad patch at position p=(y,x)
__global__ __launch_bounds__(256) void k_gather_xp(const float* __restrict__ f,
                                                   float* __restrict__ Xp, int b0) {
    int bi = b0 + blockIdx.z;
    float* out = Xp + (size_t)blockIdx.z * NXP;
    int idx = blockIdx.x * 256 + threadIdx.x;
    if (idx >= (int)NXP) return;
    int p = idx / KRED, G = idx % KRED;
    int y = p / IW, x = p % IW;
    int k1 = G / 384, k2 = (G / 128) % 3, c = G & 127;
    int u = y + k1 - 1, v = x + k2 - 1;
    float val = 0.f;
    if (u >= 0 && u < IH && v >= 0 && v < IW)
        val = f[(((size_t)bi * CS + c) * HS + 2 * u) * HS + 2 * v];
    out[idx] = val;
}

// W flat buffer == A_w_flat (the scrambled reshape is identity on flat index).
// F: p2=F/2304 -> (i=p2/384, j=(p2/128)%3, c=p2%128), s=F%2304 -> (y,x); val=pad_bd[c,y+i,x+j]
__global__ __launch_bounds__(256) void k_gather_w(const float* __restrict__ b,
                                                  float* __restrict__ W, int b0) {
    int bi = b0 + blockIdx.z;
    float* out = W + (size_t)blockIdx.z * NW;
    int idx = blockIdx.x * 256 + threadIdx.x;
    if (idx >= (int)NW) return;
    int p2 = idx / LTOT, s = idx % LTOT;
    int i = p2 / 384, j = (p2 / 128) % 3, c = p2 & 127;
    int u = s / IW + i - 1, v = s % IW + j - 1;
    float val = 0.f;
    if (u >= 0 && u < IH && v >= 0 && v < IW)
        val = b[(((size_t)bi * CS + c) * HS + 2 * u) * HS + 2 * v];
    out[idx] = val;
}

// R flat buffer == A_raw_flat. F: pr=F/2304 -> (i=pr/512, j=(pr/128)%4, c=pr%128), s=F%2304 -> (y,x)
// val = b_fullres[c, 2y+i-1, 2x+j-1] (zero pad)
__global__ __launch_bounds__(256) void k_gather_r(const float* __restrict__ b,
                                                  float* __restrict__ R, int b0) {
    int bi = b0 + blockIdx.z;
    float* out = R + (size_t)blockIdx.z * NR;
    int idx = blockIdx.x * 256 + threadIdx.x;
    if (idx >= (int)NR) return;
    int pr = idx / LTOT, s = idx % LTOT;
    int i = pr / 512, j = (pr / 128) & 3, c = pr & 127;
    int Y0 = 2 * (s / IW) + i - 1, X0 = 2 * (s % IW) + j - 1;
    float val = 0.f;
    if (Y0 >= 0 && Y0 < HS && X0 >= 0 && X0 < HS)
        val = b[(((size_t)bi * CS + c) * HS + Y0) * HS + X0];
    out[idx] = val;
}

// mm[q]: mean over 9 flat-scrambled mask-patch values; mm = (mean(1-m) < 0.85)
__global__ __launch_bounds__(256) void k_mm(const float* __restrict__ mask,
                                            float* __restrict__ mmv, int b0) {
    int bi = b0 + blockIdx.z;
    float* out = mmv + (size_t)blockIdx.z * NMM;
    int q = blockIdx.x * 256 + threadIdx.x;
    if (q >= LTOT) return;
    float ssum = 0.f;
    for (int t = 0; t < 9; t++) {
        int F = q * 9 + t;
        int pm = F / LTOT, s = F % LTOT;
        int i = pm / 3, j = pm % 3;
        int u = s / IW + i - 1, v = s % IW + j - 1;
        float val = 0.f;
        if (u >= 0 && u < IH && v >= 0 && v < IW)
            val = mask[((size_t)bi * HS + 2 * u) * HS + 2 * v];
        ssum += 1.0f - val;
    }
    out[q] = (ssum / 9.0f < 0.85f) ? 1.0f : 0.0f;
}

// normalize W rows: norm[l]=sqrt(sum_G W^2 + 1e-8); W /= max(norm,1e-4)
__global__ __launch_bounds__(256) void k_norm_w(float* __restrict__ Wg) {
    float* W = Wg + (size_t)blockIdx.z * NW;
    int l = blockIdx.x, t = threadIdx.x;
    __shared__ float red[256];
    float s = 0.f;
    for (int G = t; G < KRED; G += 256) { float w = W[(size_t)l * KRED + G]; s += w * w; }
    red[t] = s; __syncthreads();
    for (int o = 128; o > 0; o >>= 1) { if (t < o) red[t] += red[t + o]; __syncthreads(); }
    float inv = 1.0f / fmaxf(sqrtf(red[0] + 1e-8f), 1e-4f);
    for (int G = t; G < KRED; G += 256) W[(size_t)l * KRED + G] *= inv;
}

// ---------------- GEMM ----------------
// BT=true:  C[m,n] = sum_k A[m*K+k]*B[n*K+k]   (NT)
// BT=false: C[m,n] = sum_k A[m*K+k]*B[k*N+n]   (NN)
template <bool BT>
__global__ __launch_bounds__(256) void k_gemm(const float* __restrict__ Ag,
                                              const float* __restrict__ Bg,
                                              float* __restrict__ Cg,
                                              size_t sA, size_t sB, size_t sC,
                                              int M, int N, int K) {
    const float* A = Ag + (size_t)blockIdx.z * sA;
    const float* B = Bg + (size_t)blockIdx.z * sB;
    float* C = Cg + (size_t)blockIdx.z * sC;
    __shared__ float As[16][129];
    __shared__ float Bs[16][129];
    int tx = threadIdx.x, ty = threadIdx.y;
    int tid = ty * 16 + tx;
    int bm = blockIdx.y * 128, bn = blockIdx.x * 128;
    float acc[8][8] = {};
    for (int kt = 0; kt < K; kt += 16) {
#pragma unroll
        for (int e = 0; e < 8; e++) {
            int i = tid + e * 256;
            int r = i >> 4, cc = i & 15;
            As[cc][r] = A[(size_t)(bm + r) * K + kt + cc];
        }
        if (BT) {
#pragma unroll
            for (int e = 0; e < 8; e++) {
                int i = tid + e * 256;
                int r = i >> 4, cc = i & 15;
                Bs[cc][r] = B[(size_t)(bn + r) * K + kt + cc];
            }
        } else {
#pragma unroll
            for (int e = 0; e < 8; e++) {
                int i = tid + e * 256;
                int r = i >> 7, cc = i & 127;
                Bs[r][cc] = B[(size_t)(kt + r) * N + bn + cc];
            }
        }
        __syncthreads();
#pragma unroll
        for (int kk = 0; kk < 16; kk++) {
            float av[8], bv[8];
#pragma unroll
            for (int i2 = 0; i2 < 8; i2++) av[i2] = As[kk][ty * 8 + i2];
#pragma unroll
            for (int j = 0; j < 8; j++) bv[j] = Bs[kk][tx * 8 + j];
#pragma unroll
            for (int i2 = 0; i2 < 8; i2++)
#pragma unroll
                for (int j = 0; j < 8; j++) acc[i2][j] += av[i2] * bv[j];
        }
        __syncthreads();
    }
    for (int i2 = 0; i2 < 8; i2++)
        for (int j = 0; j < 8; j++)
            C[(size_t)(bm + ty * 8 + i2) * N + bn + tx * 8 + j] = acc[i2][j];
}

// ---------------- fuse ----------------
__global__ __launch_bounds__(256) void k_fuse1(const float* __restrict__ Sg,
                                               float* __restrict__ Dg) {
    const float* S = Sg + (size_t)blockIdx.z * NS;
    float* D = Dg + (size_t)blockIdx.z * NS;
    size_t idx = (size_t)blockIdx.x * 256 + threadIdx.x;
    if (idx >= NS) return;
    int A = (int)(idx / LTOT), Bc = (int)(idx % LTOT);
    float s = S[idx];
    if (A >= 1 && Bc >= 1) s += S[idx - LTOT - 1];
    if (A < LTOT - 1 && Bc < LTOT - 1) s += S[idx + LTOT + 1];
    D[idx] = s;
}

__device__ __forceinline__ int permi(int a) { return (a % 48) * 48 + a / 48; }

__global__ __launch_bounds__(256) void k_fuse2(const float* __restrict__ Sg,
                                               float* __restrict__ Dg) {
    const float* S1 = Sg + (size_t)blockIdx.z * NS;
    float* D = Dg + (size_t)blockIdx.z * NS;
    size_t idx = (size_t)blockIdx.x * 256 + threadIdx.x;
    if (idx >= NS) return;
    int A = (int)(idx / LTOT), Bc = (int)(idx % LTOT);
    int At = permi(A), Bt = permi(Bc);
    float s = S1[idx];
    if (At >= 1 && Bt >= 1)
        s += S1[(size_t)permi(At - 1) * LTOT + permi(Bt - 1)];
    if (At < LTOT - 1 && Bt < LTOT - 1)
        s += S1[(size_t)permi(At + 1) * LTOT + permi(Bt + 1)];
    D[idx] = s;
}

// ---------------- softmax + argmax + offsets ----------------
__global__ __launch_bounds__(256) void k_softmax(float* __restrict__ Sg,
                                                 const float* __restrict__ mmg,
                                                 float* __restrict__ offout, int b0) {
    int bi = b0 + blockIdx.z;
    float* S = Sg + (size_t)blockIdx.z * NS;
    const float* mm = mmg + (size_t)blockIdx.z * NMM;
    int l = blockIdx.x, t = threadIdx.x;
    __shared__ float red[256];
    __shared__ int redi[256];
    float* row = S + (size_t)l * LTOT;
    // max of v = S2*mm*10
    float mx = -1e30f;
    for (int p = t; p < LTOT; p += 256) mx = fmaxf(mx, row[p] * mm[p] * 10.0f);
    red[t] = mx; __syncthreads();
    for (int o = 128; o > 0; o >>= 1) { if (t < o) red[t] = fmaxf(red[t], red[t + o]); __syncthreads(); }
    mx = red[0]; __syncthreads();
    // sum of exp(v-mx) over ALL columns (including masked ones, matching jax.nn.softmax)
    float sm = 0.f;
    for (int p = t; p < LTOT; p += 256) sm += expf(row[p] * mm[p] * 10.0f - mx);
    red[t] = sm; __syncthreads();
    for (int o = 128; o > 0; o >>= 1) { if (t < o) red[t] += red[t + o]; __syncthreads(); }
    float Z = red[0]; __syncthreads();
    // a = (exp(v-mx)/Z)*mm ; write back in place; argmax (first-index rule)
    float bv = -1.0f; int bidx2 = 0;
    for (int p = t; p < LTOT; p += 256) {
        float e = expf(row[p] * mm[p] * 10.0f - mx);
        float a = (e / Z) * mm[p];
        row[p] = a;
        if (a > bv) { bv = a; bidx2 = p; }
    }
    red[t] = bv; redi[t] = bidx2; __syncthreads();
    for (int o = 128; o > 0; o >>= 1) {
        if (t < o) {
            if (red[t + o] > red[t] || (red[t + o] == red[t] && redi[t + o] < redi[t])) {
                red[t] = red[t + o]; redi[t] = redi[t + o];
            }
        }
        __syncthreads();
    }
    if (t == 0) {
        int off = redi[0];
        int ly = l / IW, lx = l % IW;
        offout[((size_t)bi * 2 + 0) * LTOT + l] = (float)(off / 96 - ly);
        offout[((size_t)bi * 2 + 1) * LTOT + l] = (float)(off % 96 - lx);
    }
}

// ---------------- transposed-conv scatter (reduced to <=4 reads of C) ----------------
__global__ __launch_bounds__(256) void k_output(const float* __restrict__ Cg,
                                                float* __restrict__ yout, int b0) {
    int bi = b0 + blockIdx.z;
    const float* C = Cg + (size_t)blockIdx.z * NC;
    int idx = blockIdx.x * 256 + threadIdx.x;
    if (idx >= CS * HS * HS) return;
    int c = idx / (HS * HS), rem = idx % (HS * HS);
    int Y = rem / HS, X = rem % HS;
    float s = 0.f;
    int pu = (Y + 1) & 1, pv = (X + 1) & 1;
    for (int a = 0; a < 2; a++) {
        int u = pu + 2 * a;
        int ly2 = Y + 1 - u;
        if (ly2 < 0) continue;
        int ly = ly2 >> 1;
        if (ly >= IH) continue;
        for (int bb = 0; bb < 2; bb++) {
            int v = pv + 2 * bb;
            int lx2 = X + 1 - v;
            if (lx2 < 0) continue;
            int lx = lx2 >> 1;
            if (lx >= IW) continue;
            s += C[(size_t)(ly * IW + lx) * CRED + u * 512 + v * 128 + c];
        }
    }
    yout[(size_t)bi * CS * HS * HS + idx] = s * 0.25f;
}

// ---------------- launch ----------------
extern "C" void kernel_launch(void* const* d_in, const int* in_sizes, int n_in,
                              void* d_out, int out_size, void* d_ws, size_t ws_size,
                              hipStream_t stream) {
    const float* f = (const float*)d_in[0];
    const float* b = (const float*)d_in[1];
    const float* mask = (const float*)d_in[2];
    float* yout = (float*)d_out;
    float* offout = yout + (size_t)4 * CS * HS * HS;

    const size_t perBatch = NXP + NW + 2 * NS + NR + NC + NMM;  // floats
    bool par = ws_size >= perBatch * 4 * sizeof(float);
    int ZB = par ? 4 : 1;
    int nloop = par ? 1 : 4;

    float* base = (float*)d_ws;
    float* Xp = base;
    float* W  = Xp + NXP * ZB;
    float* S  = W + NW * ZB;
    float* S2 = S + NS * ZB;
    float* R  = S2 + NS * ZB;
    float* Cc = R + NR * ZB;
    float* mmv = Cc + NC * ZB;

    dim3 blk256(256, 1, 1);
    dim3 blk2d(16, 16, 1);

    for (int it = 0; it < nloop; ++it) {
        int b0 = par ? 0 : it;
        k_gather_xp<<<dim3((unsigned)((NXP + 255) / 256), 1, ZB), blk256, 0, stream>>>(f, Xp, b0);
        k_gather_w<<<dim3((unsigned)((NW + 255) / 256), 1, ZB), blk256, 0, stream>>>(b, W, b0);
        k_norm_w<<<dim3(LTOT, 1, ZB), blk256, 0, stream>>>(W);
        k_mm<<<dim3((LTOT + 255) / 256, 1, ZB), blk256, 0, stream>>>(mask, mmv, b0);
        // S[l,p] = Wn . Xp^T : M=N=2304, K=1152 (NT)
        k_gemm<true><<<dim3(LTOT / 128, LTOT / 128, ZB), blk2d, 0, stream>>>(
            W, Xp, S, NW, NXP, NS, LTOT, LTOT, KRED);
        k_fuse1<<<dim3((unsigned)((NS + 255) / 256), 1, ZB), blk256, 0, stream>>>(S, S2);
        k_fuse2<<<dim3((unsigned)((NS + 255) / 256), 1, ZB), blk256, 0, stream>>>(S2, S);
        k_softmax<<<dim3(LTOT, 1, ZB), blk256, 0, stream>>>(S, mmv, offout, b0);
        k_gather_r<<<dim3((unsigned)((NR + 255) / 256), 1, ZB), blk256, 0, stream>>>(b, R, b0);
        // C[l,G2] = A . R : M=2304, N=2048, K=2304 (NN)
        k_gemm<false><<<dim3(CRED / 128, LTOT / 128, ZB), blk2d, 0, stream>>>(
            S, R, Cc, NS, NR, NC, LTOT, CRED, LTOT);
        k_output<<<dim3((CS * HS * HS + 255) / 256, 1, ZB), blk256, 0, stream>>>(Cc, yout, b0);
    }
}

// Round 2
// 877.794 us; speedup vs baseline: 5.6799x; 5.6799x over previous
//
#include <hip/hip_runtime.h>
#include <hip/hip_bf16.h>
#include <math.h>

#define IH 48
#define IW 48
#define LTOT 2304      // 48*48
#define CS 128
#define HS 96
#define KRED 1152      // 3*3*128
#define CRED 2048      // 4*4*128

typedef unsigned short u16;
typedef __attribute__((ext_vector_type(8))) short short8;
typedef __attribute__((ext_vector_type(8))) unsigned short ushort8;
typedef __attribute__((ext_vector_type(4))) float floatx4;

#define NS    ((size_t)LTOT*LTOT)     // 5,308,416
#define PLANE ((size_t)LTOT*KRED)     // 2,654,208
#define NRT   ((size_t)CRED*LTOT)     // 4,718,592
#define NCC   ((size_t)LTOT*CRED)

// ---- region layout (bytes), per batch slice ----
#define OFF_APL  ((size_t)0)                    // 3 bf16 planes, 15,925,248 B  (alias: attb 10.6MB)
#define OFF_BPL  ((size_t)15925248)             // 3 bf16 planes               (alias: Rt 9.44MB)
#define OFF_S    ((size_t)31850496)             // NS fp32 = 21,233,664 B
#define OFF_S2   ((size_t)53084160)             // NS fp32                     (alias: C 18.87MB)
#define OFF_SM   ((size_t)74317824)             // ninv(2304 f32) + mmv(2304 f32)
#define REGION   ((size_t)74350592)

__device__ __forceinline__ u16 f2bf(float v) {
    __hip_bfloat16 h = __float2bfloat16(v);
    return *reinterpret_cast<u16*>(&h);
}
__device__ __forceinline__ float bf2f(u16 b) {
    __hip_bfloat16 h = *reinterpret_cast<__hip_bfloat16*>(&b);
    return __bfloat162float(h);
}
__device__ __forceinline__ void split3(float v, u16& a, u16& b, u16& c) {
    a = f2bf(v); float r = v - bf2f(a);
    b = f2bf(r); r -= bf2f(b);
    c = f2bf(r);
}

// ---------------- norm of W rows (gather-reduce) ----------------
__global__ __launch_bounds__(256) void k_wnorm(const float* __restrict__ b,
                                               float* __restrict__ ninvg,
                                               int b0, size_t zsF) {
    int bi = b0 + blockIdx.z;
    float* ninv = ninvg + (size_t)blockIdx.z * zsF;
    int l = blockIdx.x, t = threadIdx.x;
    __shared__ float red[256];
    float ss = 0.f;
    for (int G = t; G < KRED; G += 256) {
        int F = l * KRED + G;
        int p2 = F / LTOT, s = F - p2 * LTOT;
        int i = p2 / 384, j = (p2 / 128) % 3, c = p2 & 127;
        int u = s / IW + i - 1, v = s % IW + j - 1;
        if (u >= 0 && u < IH && v >= 0 && v < IW) {
            float w = b[(((size_t)bi * CS + c) * HS + 2 * u) * HS + 2 * v];
            ss += w * w;
        }
    }
    red[t] = ss; __syncthreads();
    for (int o = 128; o > 0; o >>= 1) { if (t < o) red[t] += red[t + o]; __syncthreads(); }
    if (t == 0) ninv[l] = 1.0f / fmaxf(sqrtf(red[0] + 1e-8f), 1e-4f);
}

// ---------------- gather + normalize + split W -> 3 bf16 planes ----------------
__global__ __launch_bounds__(256) void k_gather_w_split(const float* __restrict__ b,
                                                        u16* __restrict__ Ag,
                                                        const float* __restrict__ ninvg,
                                                        int b0, size_t zsU, size_t zsF) {
    int bi = b0 + blockIdx.z;
    u16* A = Ag + (size_t)blockIdx.z * zsU;
    const float* ninv = ninvg + (size_t)blockIdx.z * zsF;
    int idx = blockIdx.x * 256 + threadIdx.x;
    if (idx >= (int)PLANE) return;
    int p2 = idx / LTOT, s = idx - p2 * LTOT;
    int i = p2 / 384, j = (p2 / 128) % 3, c = p2 & 127;
    int u = s / IW + i - 1, v = s % IW + j - 1;
    float val = 0.f;
    if (u >= 0 && u < IH && v >= 0 && v < IW)
        val = b[(((size_t)bi * CS + c) * HS + 2 * u) * HS + 2 * v];
    val *= ninv[idx / KRED];
    u16 h1, h2, h3; split3(val, h1, h2, h3);
    A[idx] = h1; A[PLANE + idx] = h2; A[2 * PLANE + idx] = h3;
}

// ---------------- gather + split Xp -> 3 bf16 planes ----------------
__global__ __launch_bounds__(256) void k_gather_x_split(const float* __restrict__ f,
                                                        u16* __restrict__ Bg,
                                                        int b0, size_t zsU) {
    int bi = b0 + blockIdx.z;
    u16* B = Bg + (size_t)blockIdx.z * zsU;
    int idx = blockIdx.x * 256 + threadIdx.x;
    if (idx >= (int)PLANE) return;
    int p = idx / KRED, G = idx - p * KRED;
    int y = p / IW, x = p % IW;
    int k1 = G / 384, k2 = (G / 128) % 3, c = G & 127;
    int u = y + k1 - 1, v = x + k2 - 1;
    float val = 0.f;
    if (u >= 0 && u < IH && v >= 0 && v < IW)
        val = f[(((size_t)bi * CS + c) * HS + 2 * u) * HS + 2 * v];
    u16 h1, h2, h3; split3(val, h1, h2, h3);
    B[idx] = h1; B[PLANE + idx] = h2; B[2 * PLANE + idx] = h3;
}

// ---------------- mask vector ----------------
__global__ __launch_bounds__(256) void k_mm(const float* __restrict__ mask,
                                            float* __restrict__ mmvg, int b0, size_t zsF) {
    int bi = b0 + blockIdx.z;
    float* out = mmvg + (size_t)blockIdx.z * zsF;
    int q = blockIdx.x * 256 + threadIdx.x;
    if (q >= LTOT) return;
    float ssum = 0.f;
    for (int t = 0; t < 9; t++) {
        int F = q * 9 + t;
        int pm = F / LTOT, s = F % LTOT;
        int i = pm / 3, j = pm % 3;
        int u = s / IW + i - 1, v = s % IW + j - 1;
        float val = 0.f;
        if (u >= 0 && u < IH && v >= 0 && v < IW)
            val = mask[((size_t)bi * HS + 2 * u) * HS + 2 * v];
        ssum += 1.0f - val;
    }
    out[q] = (ssum / 9.0f < 0.85f) ? 1.0f : 0.0f;
}

// ---------------- gather raw patches, pre-transposed: Rt[n][k] ----------------
__global__ __launch_bounds__(256) void k_gather_rt(const float* __restrict__ b,
                                                   u16* __restrict__ Rtg,
                                                   int b0, size_t zsU) {
    int bi = b0 + blockIdx.z;
    u16* Rt = Rtg + (size_t)blockIdx.z * zsU;
    size_t idx = (size_t)blockIdx.x * 256 + threadIdx.x;
    if (idx >= NRT) return;
    int n = (int)(idx / LTOT), k = (int)(idx - (size_t)n * LTOT);
    size_t F = (size_t)k * CRED + n;            // flat index of round-1 R buffer
    int pr = (int)(F / LTOT);
    int s = (int)(F - (size_t)pr * LTOT);
    int i = pr / 512, j = (pr / 128) & 3, c = pr & 127;
    int Y0 = 2 * (s / IW) + i - 1, X0 = 2 * (s % IW) + j - 1;
    float val = 0.f;
    if (Y0 >= 0 && Y0 < HS && X0 >= 0 && X0 < HS)
        val = b[(((size_t)bi * CS + c) * HS + Y0) * HS + X0];
    Rt[idx] = f2bf(val);
}

// ---------------- MFMA GEMM (NT): C[m,n] = sum_k A[m,k]*B[n,k], split-planes ----------------
// NP=3: A,B each 3 bf16 planes; accumulate 6 products (i+j<=4), small-first.
// NP=1: plain bf16.
template <int NP>
__global__ __launch_bounds__(256) void k_gemm_mfma(const u16* __restrict__ Ag,
                                                   const u16* __restrict__ Bg,
                                                   float* __restrict__ Cg,
                                                   size_t zsA, size_t zsB, size_t zsC,
                                                   size_t planeStride,
                                                   int M, int N, int K) {
    const u16* A = Ag + (size_t)blockIdx.z * zsA;
    const u16* B = Bg + (size_t)blockIdx.z * zsB;
    float* C = Cg + (size_t)blockIdx.z * zsC;
    __shared__ u16 As[NP * 4096];
    __shared__ u16 Bs[NP * 4096];
    const int tid = threadIdx.x;
    const int lane = tid & 63, wave = tid >> 6;
    const int wr = (wave >> 1) * 64, wc = (wave & 1) * 64;
    const int lrow = lane & 15, lk = (lane >> 4) * 8;
    const int bm = blockIdx.y * 128, bn = blockIdx.x * 128;

    floatx4 acc[4][4];
#pragma unroll
    for (int i = 0; i < 4; i++)
#pragma unroll
        for (int j = 0; j < 4; j++) acc[i][j] = (floatx4){0.f, 0.f, 0.f, 0.f};

    for (int kt = 0; kt < K; kt += 32) {
        ushort8 st[NP * 4];
#pragma unroll
        for (int e = 0; e < NP * 4; ++e) {
            const int side = (e >= NP * 2);
            int w = (side ? e - NP * 2 : e) * 256 + tid;
            int p = w >> 9;
            int c = w & 511;
            int row = c >> 2, slot = c & 3;
            const u16* src = (side ? B : A) + (size_t)p * planeStride
                + (size_t)((side ? bn : bm) + row) * K + kt + slot * 8;
            st[e] = *(const ushort8*)src;
        }
        __syncthreads();   // prior compute finished reading LDS
#pragma unroll
        for (int e = 0; e < NP * 4; ++e) {
            const int side = (e >= NP * 2);
            int w = (side ? e - NP * 2 : e) * 256 + tid;
            int p = w >> 9;
            int c = w & 511;
            *(ushort8*)&((side ? Bs : As)[p * 4096 + c * 8]) = st[e];
        }
        __syncthreads();

        short8 af[NP][4];
#pragma unroll
        for (int p = 0; p < NP; ++p)
#pragma unroll
            for (int mi = 0; mi < 4; ++mi)
                af[p][mi] = *(const short8*)&As[p * 4096 + (wr + mi * 16 + lrow) * 32 + lk];
#pragma unroll
        for (int ni = 0; ni < 4; ++ni) {
            short8 bfr[NP];
#pragma unroll
            for (int p = 0; p < NP; ++p)
                bfr[p] = *(const short8*)&Bs[p * 4096 + (wc + ni * 16 + lrow) * 32 + lk];
#pragma unroll
            for (int mi = 0; mi < 4; ++mi) {
                if constexpr (NP == 1) {
                    acc[mi][ni] = __builtin_amdgcn_mfma_f32_16x16x32_bf16(af[0][mi], bfr[0], acc[mi][ni], 0, 0, 0);
                } else {
                    // small-first: (2,0),(0,2),(1,1),(1,0),(0,1),(0,0)
                    acc[mi][ni] = __builtin_amdgcn_mfma_f32_16x16x32_bf16(af[2][mi], bfr[0], acc[mi][ni], 0, 0, 0);
                    acc[mi][ni] = __builtin_amdgcn_mfma_f32_16x16x32_bf16(af[0][mi], bfr[2], acc[mi][ni], 0, 0, 0);
                    acc[mi][ni] = __builtin_amdgcn_mfma_f32_16x16x32_bf16(af[1][mi], bfr[1], acc[mi][ni], 0, 0, 0);
                    acc[mi][ni] = __builtin_amdgcn_mfma_f32_16x16x32_bf16(af[1][mi], bfr[0], acc[mi][ni], 0, 0, 0);
                    acc[mi][ni] = __builtin_amdgcn_mfma_f32_16x16x32_bf16(af[0][mi], bfr[1], acc[mi][ni], 0, 0, 0);
                    acc[mi][ni] = __builtin_amdgcn_mfma_f32_16x16x32_bf16(af[0][mi], bfr[0], acc[mi][ni], 0, 0, 0);
                }
            }
        }
    }

    const int r0 = bm + wr + (lane >> 4) * 4;
    const int c0 = bn + wc + (lane & 15);
#pragma unroll
    for (int mi = 0; mi < 4; ++mi)
#pragma unroll
        for (int ni = 0; ni < 4; ++ni)
#pragma unroll
            for (int j = 0; j < 4; ++j)
                C[(size_t)(r0 + mi * 16 + j) * N + (c0 + ni * 16)] = acc[mi][ni][j];
}

// ---------------- fuse ----------------
__global__ __launch_bounds__(256) void k_fuse1(const float* __restrict__ Sg,
                                               float* __restrict__ Dg, size_t zsF) {
    const float* S = Sg + (size_t)blockIdx.z * zsF;
    float* D = Dg + (size_t)blockIdx.z * zsF;
    size_t idx = (size_t)blockIdx.x * 256 + threadIdx.x;
    if (idx >= NS) return;
    int A = (int)(idx / LTOT), Bc = (int)(idx % LTOT);
    float s = S[idx];
    if (A >= 1 && Bc >= 1) s += S[idx - LTOT - 1];
    if (A < LTOT - 1 && Bc < LTOT - 1) s += S[idx + LTOT + 1];
    D[idx] = s;
}

__device__ __forceinline__ int permi(int a) { return (a % 48) * 48 + a / 48; }

__global__ __launch_bounds__(256) void k_fuse2(const float* __restrict__ Sg,
                                               float* __restrict__ Dg, size_t zsF) {
    const float* S1 = Sg + (size_t)blockIdx.z * zsF;
    float* D = Dg + (size_t)blockIdx.z * zsF;
    size_t idx = (size_t)blockIdx.x * 256 + threadIdx.x;
    if (idx >= NS) return;
    int A = (int)(idx / LTOT), Bc = (int)(idx % LTOT);
    int At = permi(A), Bt = permi(Bc);
    float s = S1[idx];
    if (At >= 1 && Bt >= 1)
        s += S1[(size_t)permi(At - 1) * LTOT + permi(Bt - 1)];
    if (At < LTOT - 1 && Bt < LTOT - 1)
        s += S1[(size_t)permi(At + 1) * LTOT + permi(Bt + 1)];
    D[idx] = s;
}

// ---------------- softmax + argmax + offsets; writes bf16 att ----------------
__global__ __launch_bounds__(256) void k_softmax(const float* __restrict__ Sg,
                                                 const float* __restrict__ mmg,
                                                 u16* __restrict__ attbg,
                                                 float* __restrict__ offout,
                                                 int b0, size_t zsF, size_t zsU) {
    int bi = b0 + blockIdx.z;
    const float* S = Sg + (size_t)blockIdx.z * zsF;
    const float* mm = mmg + (size_t)blockIdx.z * zsF;
    u16* attb = attbg + (size_t)blockIdx.z * zsU;
    int l = blockIdx.x, t = threadIdx.x;
    __shared__ float red[256];
    __shared__ int redi[256];
    const float* row = S + (size_t)l * LTOT;
    u16* arow = attb + (size_t)l * LTOT;
    float mx = -1e30f;
    for (int p = t; p < LTOT; p += 256) mx = fmaxf(mx, row[p] * mm[p] * 10.0f);
    red[t] = mx; __syncthreads();
    for (int o = 128; o > 0; o >>= 1) { if (t < o) red[t] = fmaxf(red[t], red[t + o]); __syncthreads(); }
    mx = red[0]; __syncthreads();
    float sm = 0.f;
    for (int p = t; p < LTOT; p += 256) sm += expf(row[p] * mm[p] * 10.0f - mx);
    red[t] = sm; __syncthreads();
    for (int o = 128; o > 0; o >>= 1) { if (t < o) red[t] += red[t + o]; __syncthreads(); }
    float Z = red[0]; __syncthreads();
    float bv = -1.0f; int bidx2 = 0;
    for (int p = t; p < LTOT; p += 256) {
        float e = expf(row[p] * mm[p] * 10.0f - mx);
        float a = (e / Z) * mm[p];
        arow[p] = f2bf(a);
        if (a > bv) { bv = a; bidx2 = p; }
    }
    red[t] = bv; redi[t] = bidx2; __syncthreads();
    for (int o = 128; o > 0; o >>= 1) {
        if (t < o) {
            if (red[t + o] > red[t] || (red[t + o] == red[t] && redi[t + o] < redi[t])) {
                red[t] = red[t + o]; redi[t] = redi[t + o];
            }
        }
        __syncthreads();
    }
    if (t == 0) {
        int off = redi[0];
        int ly = l / IW, lx = l % IW;
        offout[((size_t)bi * 2 + 0) * LTOT + l] = (float)(off / 96 - ly);
        offout[((size_t)bi * 2 + 1) * LTOT + l] = (float)(off % 96 - lx);
    }
}

// ---------------- transposed-conv reduction ----------------
__global__ __launch_bounds__(256) void k_output(const float* __restrict__ Cg,
                                                float* __restrict__ yout,
                                                int b0, size_t zsF) {
    int bi = b0 + blockIdx.z;
    const float* C = Cg + (size_t)blockIdx.z * zsF;
    int idx = blockIdx.x * 256 + threadIdx.x;
    if (idx >= CS * HS * HS) return;
    int c = idx / (HS * HS), rem = idx % (HS * HS);
    int Y = rem / HS, X = rem % HS;
    float s = 0.f;
    int pu = (Y + 1) & 1, pv = (X + 1) & 1;
    for (int a = 0; a < 2; a++) {
        int u = pu + 2 * a;
        int ly2 = Y + 1 - u;
        if (ly2 < 0) continue;
        int ly = ly2 >> 1;
        if (ly >= IH) continue;
        for (int bb = 0; bb < 2; bb++) {
            int v = pv + 2 * bb;
            int lx2 = X + 1 - v;
            if (lx2 < 0) continue;
            int lx = lx2 >> 1;
            if (lx >= IW) continue;
            s += C[(size_t)(ly * IW + lx) * CRED + u * 512 + v * 128 + c];
        }
    }
    yout[(size_t)bi * CS * HS * HS + idx] = s * 0.25f;
}

// ---------------- launch ----------------
extern "C" void kernel_launch(void* const* d_in, const int* in_sizes, int n_in,
                              void* d_out, int out_size, void* d_ws, size_t ws_size,
                              hipStream_t stream) {
    const float* f = (const float*)d_in[0];
    const float* b = (const float*)d_in[1];
    const float* mask = (const float*)d_in[2];
    float* yout = (float*)d_out;
    float* offout = yout + (size_t)4 * CS * HS * HS;

    int ZB, nloop;
    if (ws_size >= 4 * REGION)      { ZB = 4; nloop = 1; }
    else if (ws_size >= 2 * REGION) { ZB = 2; nloop = 2; }
    else                            { ZB = 1; nloop = 4; }

    char* base = (char*)d_ws;
    u16*   Apl  = (u16*)(base + OFF_APL);
    u16*   Bpl  = (u16*)(base + OFF_BPL);
    float* S    = (float*)(base + OFF_S);
    float* S2   = (float*)(base + OFF_S2);
    float* ninv = (float*)(base + OFF_SM);
    float* mmv  = ninv + LTOT;
    u16*   attb = Apl;   // alias (A planes dead after gemm1)
    u16*   Rt   = Bpl;   // alias (B planes dead after gemm1)
    float* Cc   = S2;    // alias (S2 dead after fuse2)

    const size_t zsU = REGION / 2;   // per-z stride in u16 elements
    const size_t zsF = REGION / 4;   // per-z stride in float elements

    dim3 blk(256, 1, 1);

    for (int it = 0; it < nloop; ++it) {
        int b0 = it * ZB;
        k_wnorm<<<dim3(LTOT, 1, ZB), blk, 0, stream>>>(b, ninv, b0, zsF);
        k_gather_w_split<<<dim3((unsigned)(PLANE / 256), 1, ZB), blk, 0, stream>>>(b, Apl, ninv, b0, zsU, zsF);
        k_gather_x_split<<<dim3((unsigned)(PLANE / 256), 1, ZB), blk, 0, stream>>>(f, Bpl, b0, zsU);
        k_mm<<<dim3((LTOT + 255) / 256, 1, ZB), blk, 0, stream>>>(mask, mmv, b0, zsF);
        // S[l,p] = Wn . Xp^T : M=N=2304, K=1152, 3-plane split, 6 products
        k_gemm_mfma<3><<<dim3(LTOT / 128, LTOT / 128, ZB), blk, 0, stream>>>(
            Apl, Bpl, S, zsU, zsU, zsF, PLANE, LTOT, LTOT, KRED);
        k_fuse1<<<dim3((unsigned)(NS / 256), 1, ZB), blk, 0, stream>>>(S, S2, zsF);
        k_fuse2<<<dim3((unsigned)(NS / 256), 1, ZB), blk, 0, stream>>>(S2, S, zsF);
        k_softmax<<<dim3(LTOT, 1, ZB), blk, 0, stream>>>(S, mmv, attb, offout, b0, zsF, zsU);
        k_gather_rt<<<dim3((unsigned)(NRT / 256), 1, ZB), blk, 0, stream>>>(b, Rt, b0, zsU);
        // C[l,G2] = att . Rt^T : M=2304, N=2048, K=2304, plain bf16
        k_gemm_mfma<1><<<dim3(CRED / 128, LTOT / 128, ZB), blk, 0, stream>>>(
            attb, Rt, Cc, zsU, zsU, zsF, PLANE, LTOT, CRED, LTOT);
        k_output<<<dim3((CS * HS * HS) / 256, 1, ZB), blk, 0, stream>>>(Cc, yout, b0, zsF);
    }
}

// Round 3
// 664.745 us; speedup vs baseline: 7.5003x; 1.3205x over previous
//
#include <hip/hip_runtime.h>
#include <hip/hip_bf16.h>
#include <math.h>

#define IH 48
#define IW 48
#define LTOT 2304      // 48*48
#define CS 128
#define HS 96
#define KRED 1152      // 3*3*128
#define CRED 2048      // 4*4*128

typedef unsigned short u16;
typedef __attribute__((ext_vector_type(8))) short short8;
typedef __attribute__((ext_vector_type(8))) unsigned short ushort8;
typedef __attribute__((ext_vector_type(4))) float floatx4;

#define NS    ((size_t)LTOT*LTOT)     // 5,308,416
#define PLANE ((size_t)LTOT*KRED)     // 2,654,208
#define NRT   ((size_t)CRED*LTOT)     // 4,718,592
#define NCC   ((size_t)LTOT*CRED)

// ---- region layout (bytes), per batch slice ----
// APL: 2 bf16 planes = 10,616,832 B (alias: attb = NS u16 = same size)
// BPL: 2 bf16 planes = 10,616,832 B (alias: Rt = 9,437,184 B)
// S  : NS fp32 = 21,233,664 B
// S2 : NS fp32 = 21,233,664 B (alias: Cc = 18,874,368 B)
#define OFF_APL  ((size_t)0)
#define OFF_BPL  ((size_t)10616832)
#define OFF_S    ((size_t)21233664)
#define OFF_S2   ((size_t)42467328)
#define OFF_SM   ((size_t)63700992)
#define REGION   ((size_t)63719424)

__device__ __forceinline__ u16 f2bf(float v) {
    __hip_bfloat16 h = __float2bfloat16(v);
    return *reinterpret_cast<u16*>(&h);
}
__device__ __forceinline__ float bf2f(u16 b) {
    __hip_bfloat16 h = *reinterpret_cast<__hip_bfloat16*>(&b);
    return __bfloat162float(h);
}
__device__ __forceinline__ void split2(float v, u16& a, u16& b) {
    a = f2bf(v);
    b = f2bf(v - bf2f(a));
}

// ---------------- norm of W rows (gather-reduce) ----------------
__global__ __launch_bounds__(256) void k_wnorm(const float* __restrict__ b,
                                               float* __restrict__ ninvg,
                                               int b0, size_t zsF) {
    int bi = b0 + blockIdx.z;
    float* ninv = ninvg + (size_t)blockIdx.z * zsF;
    int l = blockIdx.x, t = threadIdx.x;
    __shared__ float red[256];
    float ss = 0.f;
    for (int G = t; G < KRED; G += 256) {
        int F = l * KRED + G;
        int p2 = F / LTOT, s = F - p2 * LTOT;
        int i = p2 / 384, j = (p2 / 128) % 3, c = p2 & 127;
        int u = s / IW + i - 1, v = s % IW + j - 1;
        if (u >= 0 && u < IH && v >= 0 && v < IW) {
            float w = b[(((size_t)bi * CS + c) * HS + 2 * u) * HS + 2 * v];
            ss += w * w;
        }
    }
    red[t] = ss; __syncthreads();
    for (int o = 128; o > 0; o >>= 1) { if (t < o) red[t] += red[t + o]; __syncthreads(); }
    if (t == 0) ninv[l] = 1.0f / fmaxf(sqrtf(red[0] + 1e-8f), 1e-4f);
}

// ---------------- gather + normalize + split W -> 2 bf16 planes ----------------
__global__ __launch_bounds__(256) void k_gather_w_split(const float* __restrict__ b,
                                                        u16* __restrict__ Ag,
                                                        const float* __restrict__ ninvg,
                                                        int b0, size_t zsU, size_t zsF) {
    int bi = b0 + blockIdx.z;
    u16* A = Ag + (size_t)blockIdx.z * zsU;
    const float* ninv = ninvg + (size_t)blockIdx.z * zsF;
    int idx = blockIdx.x * 256 + threadIdx.x;
    if (idx >= (int)PLANE) return;
    int p2 = idx / LTOT, s = idx - p2 * LTOT;
    int i = p2 / 384, j = (p2 / 128) % 3, c = p2 & 127;
    int u = s / IW + i - 1, v = s % IW + j - 1;
    float val = 0.f;
    if (u >= 0 && u < IH && v >= 0 && v < IW)
        val = b[(((size_t)bi * CS + c) * HS + 2 * u) * HS + 2 * v];
    val *= ninv[idx / KRED];
    u16 h1, h2; split2(val, h1, h2);
    A[idx] = h1; A[PLANE + idx] = h2;
}

// ---------------- gather + split Xp -> 2 bf16 planes ----------------
__global__ __launch_bounds__(256) void k_gather_x_split(const float* __restrict__ f,
                                                        u16* __restrict__ Bg,
                                                        int b0, size_t zsU) {
    int bi = b0 + blockIdx.z;
    u16* B = Bg + (size_t)blockIdx.z * zsU;
    int idx = blockIdx.x * 256 + threadIdx.x;
    if (idx >= (int)PLANE) return;
    int p = idx / KRED, G = idx - p * KRED;
    int y = p / IW, x = p % IW;
    int k1 = G / 384, k2 = (G / 128) % 3, c = G & 127;
    int u = y + k1 - 1, v = x + k2 - 1;
    float val = 0.f;
    if (u >= 0 && u < IH && v >= 0 && v < IW)
        val = f[(((size_t)bi * CS + c) * HS + 2 * u) * HS + 2 * v];
    u16 h1, h2; split2(val, h1, h2);
    B[idx] = h1; B[PLANE + idx] = h2;
}

// ---------------- mask vector ----------------
__global__ __launch_bounds__(256) void k_mm(const float* __restrict__ mask,
                                            float* __restrict__ mmvg, int b0, size_t zsF) {
    int bi = b0 + blockIdx.z;
    float* out = mmvg + (size_t)blockIdx.z * zsF;
    int q = blockIdx.x * 256 + threadIdx.x;
    if (q >= LTOT) return;
    float ssum = 0.f;
    for (int t = 0; t < 9; t++) {
        int F = q * 9 + t;
        int pm = F / LTOT, s = F % LTOT;
        int i = pm / 3, j = pm % 3;
        int u = s / IW + i - 1, v = s % IW + j - 1;
        float val = 0.f;
        if (u >= 0 && u < IH && v >= 0 && v < IW)
            val = mask[((size_t)bi * HS + 2 * u) * HS + 2 * v];
        ssum += 1.0f - val;
    }
    out[q] = (ssum / 9.0f < 0.85f) ? 1.0f : 0.0f;
}

// ---------------- gather raw patches, pre-transposed: Rt[n][k] ----------------
__global__ __launch_bounds__(256) void k_gather_rt(const float* __restrict__ b,
                                                   u16* __restrict__ Rtg,
                                                   int b0, size_t zsU) {
    int bi = b0 + blockIdx.z;
    u16* Rt = Rtg + (size_t)blockIdx.z * zsU;
    size_t idx = (size_t)blockIdx.x * 256 + threadIdx.x;
    if (idx >= NRT) return;
    int n = (int)(idx / LTOT), k = (int)(idx - (size_t)n * LTOT);
    size_t F = (size_t)k * CRED + n;            // flat index of conceptual R buffer
    int pr = (int)(F / LTOT);
    int s = (int)(F - (size_t)pr * LTOT);
    int i = pr / 512, j = (pr / 128) & 3, c = pr & 127;
    int Y0 = 2 * (s / IW) + i - 1, X0 = 2 * (s % IW) + j - 1;
    float val = 0.f;
    if (Y0 >= 0 && Y0 < HS && X0 >= 0 && X0 < HS)
        val = b[(((size_t)bi * CS + c) * HS + Y0) * HS + X0];
    Rt[idx] = f2bf(val);
}

// ---------------- MFMA GEMM (NT): C[m,n] = sum_k A[m,k]*B[n,k] ----------------
// Tile 128x128, BK=64, 4 waves (2x2). LDS per side: NP planes of [128 rows][64 k] u16,
// XOR-8 swizzled: physical 16B-slot = slot ^ (row&7)  -> bank-group = slot' only,
// so each 16-lane fragment-read group hits 8 groups x2 lanes (free 2-way).
// NP=2: 3-product split-2 (hi*hi + hi*lo + lo*hi), small-first accumulate.
// NP=1: plain bf16.
template <int NP>
__global__ __launch_bounds__(256) void k_gemm_mfma(const u16* __restrict__ Ag,
                                                   const u16* __restrict__ Bg,
                                                   float* __restrict__ Cg,
                                                   size_t zsA, size_t zsB, size_t zsC,
                                                   size_t planeStride,
                                                   int M, int N, int K) {
    const u16* A = Ag + (size_t)blockIdx.z * zsA;
    const u16* B = Bg + (size_t)blockIdx.z * zsB;
    float* C = Cg + (size_t)blockIdx.z * zsC;
    __shared__ u16 lds[NP * 8192 * 2];
    u16* As = lds;
    u16* Bs = lds + NP * 8192;
    const int tid = threadIdx.x;
    const int lane = tid & 63;
    const int wave = tid >> 6;
    const int wr = (wave >> 1) * 64, wc = (wave & 1) * 64;
    const int lrow = lane & 15, lq = lane >> 4;   // fragment: row=..+lrow, k=ks*32+lq*8
    const int bm = blockIdx.y * 128, bn = blockIdx.x * 128;

    floatx4 acc[4][4];
#pragma unroll
    for (int i = 0; i < 4; i++)
#pragma unroll
        for (int j = 0; j < 4; j++) acc[i][j] = (floatx4){0.f, 0.f, 0.f, 0.f};

    for (int kt = 0; kt < K; kt += 64) {
        ushort8 stA[NP * 4], stB[NP * 4];
#pragma unroll
        for (int e = 0; e < NP * 4; ++e) {
            int g = e * 256 + tid;
            int p = g >> 10;             // plane
            int gg = g & 1023;           // chunk within plane: 128 rows x 8 slots
            int row = gg >> 3, slot = gg & 7;
            stA[e] = *(const ushort8*)(A + (size_t)p * planeStride + (size_t)(bm + row) * K + kt + slot * 8);
            stB[e] = *(const ushort8*)(B + (size_t)p * planeStride + (size_t)(bn + row) * K + kt + slot * 8);
        }
        __syncthreads();   // prior compute finished reading LDS
#pragma unroll
        for (int e = 0; e < NP * 4; ++e) {
            int g = e * 256 + tid;
            int p = g >> 10;
            int gg = g & 1023;
            int row = gg >> 3, slot = gg & 7;
            int dst = p * 8192 + row * 64 + ((slot ^ (row & 7)) << 3);
            *(ushort8*)&As[dst] = stA[e];
            *(ushort8*)&Bs[dst] = stB[e];
        }
        __syncthreads();

#pragma unroll
        for (int ks = 0; ks < 2; ++ks) {
            short8 af[NP][4];
#pragma unroll
            for (int p = 0; p < NP; ++p)
#pragma unroll
                for (int mi = 0; mi < 4; ++mi) {
                    int row = wr + mi * 16 + lrow;
                    af[p][mi] = *(const short8*)&As[p * 8192 + row * 64 + ((((ks << 2) | lq) ^ (row & 7)) << 3)];
                }
#pragma unroll
            for (int ni = 0; ni < 4; ++ni) {
                short8 bfr[NP];
                int rowb = wc + ni * 16 + lrow;
                int bslot = ((((ks << 2) | lq) ^ (rowb & 7)) << 3);
#pragma unroll
                for (int p = 0; p < NP; ++p)
                    bfr[p] = *(const short8*)&Bs[p * 8192 + rowb * 64 + bslot];
#pragma unroll
                for (int mi = 0; mi < 4; ++mi) {
                    if constexpr (NP == 1) {
                        acc[mi][ni] = __builtin_amdgcn_mfma_f32_16x16x32_bf16(af[0][mi], bfr[0], acc[mi][ni], 0, 0, 0);
                    } else {
                        // small-first: lo*hi, hi*lo, hi*hi
                        acc[mi][ni] = __builtin_amdgcn_mfma_f32_16x16x32_bf16(af[1][mi], bfr[0], acc[mi][ni], 0, 0, 0);
                        acc[mi][ni] = __builtin_amdgcn_mfma_f32_16x16x32_bf16(af[0][mi], bfr[1], acc[mi][ni], 0, 0, 0);
                        acc[mi][ni] = __builtin_amdgcn_mfma_f32_16x16x32_bf16(af[0][mi], bfr[0], acc[mi][ni], 0, 0, 0);
                    }
                }
            }
        }
    }

    const int r0 = bm + wr + (lane >> 4) * 4;
    const int c0 = bn + wc + (lane & 15);
#pragma unroll
    for (int mi = 0; mi < 4; ++mi)
#pragma unroll
        for (int ni = 0; ni < 4; ++ni)
#pragma unroll
            for (int j = 0; j < 4; ++j)
                C[(size_t)(r0 + mi * 16 + j) * N + (c0 + ni * 16)] = acc[mi][ni][j];
}

// ---------------- fuse ----------------
__global__ __launch_bounds__(256) void k_fuse1(const float* __restrict__ Sg,
                                               float* __restrict__ Dg, size_t zsF) {
    const float* S = Sg + (size_t)blockIdx.z * zsF;
    float* D = Dg + (size_t)blockIdx.z * zsF;
    size_t idx = (size_t)blockIdx.x * 256 + threadIdx.x;
    if (idx >= NS) return;
    int A = (int)(idx / LTOT), Bc = (int)(idx % LTOT);
    float s = S[idx];
    if (A >= 1 && Bc >= 1) s += S[idx - LTOT - 1];
    if (A < LTOT - 1 && Bc < LTOT - 1) s += S[idx + LTOT + 1];
    D[idx] = s;
}

__device__ __forceinline__ int permi(int a) { return (a % 48) * 48 + a / 48; }

__global__ __launch_bounds__(256) void k_fuse2(const float* __restrict__ Sg,
                                               float* __restrict__ Dg, size_t zsF) {
    const float* S1 = Sg + (size_t)blockIdx.z * zsF;
    float* D = Dg + (size_t)blockIdx.z * zsF;
    size_t idx = (size_t)blockIdx.x * 256 + threadIdx.x;
    if (idx >= NS) return;
    int A = (int)(idx / LTOT), Bc = (int)(idx % LTOT);
    int At = permi(A), Bt = permi(Bc);
    float s = S1[idx];
    if (At >= 1 && Bt >= 1)
        s += S1[(size_t)permi(At - 1) * LTOT + permi(Bt - 1)];
    if (At < LTOT - 1 && Bt < LTOT - 1)
        s += S1[(size_t)permi(At + 1) * LTOT + permi(Bt + 1)];
    D[idx] = s;
}

// ---------------- softmax + argmax + offsets; writes bf16 att ----------------
__global__ __launch_bounds__(256) void k_softmax(const float* __restrict__ Sg,
                                                 const float* __restrict__ mmg,
                                                 u16* __restrict__ attbg,
                                                 float* __restrict__ offout,
                                                 int b0, size_t zsF, size_t zsU) {
    int bi = b0 + blockIdx.z;
    const float* S = Sg + (size_t)blockIdx.z * zsF;
    const float* mm = mmg + (size_t)blockIdx.z * zsF;
    u16* attb = attbg + (size_t)blockIdx.z * zsU;
    int l = blockIdx.x, t = threadIdx.x;
    __shared__ float red[256];
    __shared__ int redi[256];
    const float* row = S + (size_t)l * LTOT;
    u16* arow = attb + (size_t)l * LTOT;
    float mx = -1e30f;
    for (int p = t; p < LTOT; p += 256) mx = fmaxf(mx, row[p] * mm[p] * 10.0f);
    red[t] = mx; __syncthreads();
    for (int o = 128; o > 0; o >>= 1) { if (t < o) red[t] = fmaxf(red[t], red[t + o]); __syncthreads(); }
    mx = red[0]; __syncthreads();
    float sm = 0.f;
    for (int p = t; p < LTOT; p += 256) sm += expf(row[p] * mm[p] * 10.0f - mx);
    red[t] = sm; __syncthreads();
    for (int o = 128; o > 0; o >>= 1) { if (t < o) red[t] += red[t + o]; __syncthreads(); }
    float Z = red[0]; __syncthreads();
    float bv = -1.0f; int bidx2 = 0;
    for (int p = t; p < LTOT; p += 256) {
        float e = expf(row[p] * mm[p] * 10.0f - mx);
        float a = (e / Z) * mm[p];
        arow[p] = f2bf(a);
        if (a > bv) { bv = a; bidx2 = p; }
    }
    red[t] = bv; redi[t] = bidx2; __syncthreads();
    for (int o = 128; o > 0; o >>= 1) {
        if (t < o) {
            if (red[t + o] > red[t] || (red[t + o] == red[t] && redi[t + o] < redi[t])) {
                red[t] = red[t + o]; redi[t] = redi[t + o];
            }
        }
        __syncthreads();
    }
    if (t == 0) {
        int off = redi[0];
        int ly = l / IW, lx = l % IW;
        offout[((size_t)bi * 2 + 0) * LTOT + l] = (float)(off / 96 - ly);
        offout[((size_t)bi * 2 + 1) * LTOT + l] = (float)(off % 96 - lx);
    }
}

// ---------------- transposed-conv reduction ----------------
__global__ __launch_bounds__(256) void k_output(const float* __restrict__ Cg,
                                                float* __restrict__ yout,
                                                int b0, size_t zsF) {
    int bi = b0 + blockIdx.z;
    const float* C = Cg + (size_t)blockIdx.z * zsF;
    int idx = blockIdx.x * 256 + threadIdx.x;
    if (idx >= CS * HS * HS) return;
    int c = idx / (HS * HS), rem = idx % (HS * HS);
    int Y = rem / HS, X = rem % HS;
    float s = 0.f;
    int pu = (Y + 1) & 1, pv = (X + 1) & 1;
    for (int a = 0; a < 2; a++) {
        int u = pu + 2 * a;
        int ly2 = Y + 1 - u;
        if (ly2 < 0) continue;
        int ly = ly2 >> 1;
        if (ly >= IH) continue;
        for (int bb = 0; bb < 2; bb++) {
            int v = pv + 2 * bb;
            int lx2 = X + 1 - v;
            if (lx2 < 0) continue;
            int lx = lx2 >> 1;
            if (lx >= IW) continue;
            s += C[(size_t)(ly * IW + lx) * CRED + u * 512 + v * 128 + c];
        }
    }
    yout[(size_t)bi * CS * HS * HS + idx] = s * 0.25f;
}

// ---------------- launch ----------------
extern "C" void kernel_launch(void* const* d_in, const int* in_sizes, int n_in,
                              void* d_out, int out_size, void* d_ws, size_t ws_size,
                              hipStream_t stream) {
    const float* f = (const float*)d_in[0];
    const float* b = (const float*)d_in[1];
    const float* mask = (const float*)d_in[2];
    float* yout = (float*)d_out;
    float* offout = yout + (size_t)4 * CS * HS * HS;

    int ZB, nloop;
    if (ws_size >= 4 * REGION)      { ZB = 4; nloop = 1; }
    else if (ws_size >= 2 * REGION) { ZB = 2; nloop = 2; }
    else                            { ZB = 1; nloop = 4; }

    char* base = (char*)d_ws;
    u16*   Apl  = (u16*)(base + OFF_APL);
    u16*   Bpl  = (u16*)(base + OFF_BPL);
    float* S    = (float*)(base + OFF_S);
    float* S2   = (float*)(base + OFF_S2);
    float* ninv = (float*)(base + OFF_SM);
    float* mmv  = ninv + LTOT;
    u16*   attb = Apl;   // alias (A planes dead after gemm1)
    u16*   Rt   = Bpl;   // alias (B planes dead after gemm1)
    float* Cc   = S2;    // alias (S2 dead after fuse2)

    const size_t zsU = REGION / 2;   // per-z stride in u16 elements
    const size_t zsF = REGION / 4;   // per-z stride in float elements

    dim3 blk(256, 1, 1);

    for (int it = 0; it < nloop; ++it) {
        int b0 = it * ZB;
        k_wnorm<<<dim3(LTOT, 1, ZB), blk, 0, stream>>>(b, ninv, b0, zsF);
        k_gather_w_split<<<dim3((unsigned)(PLANE / 256), 1, ZB), blk, 0, stream>>>(b, Apl, ninv, b0, zsU, zsF);
        k_gather_x_split<<<dim3((unsigned)(PLANE / 256), 1, ZB), blk, 0, stream>>>(f, Bpl, b0, zsU);
        k_mm<<<dim3((LTOT + 255) / 256, 1, ZB), blk, 0, stream>>>(mask, mmv, b0, zsF);
        // S[l,p] = Wn . Xp^T : M=N=2304, K=1152, split-2, 3 products
        k_gemm_mfma<2><<<dim3(LTOT / 128, LTOT / 128, ZB), blk, 0, stream>>>(
            Apl, Bpl, S, zsU, zsU, zsF, PLANE, LTOT, LTOT, KRED);
        k_fuse1<<<dim3((unsigned)(NS / 256), 1, ZB), blk, 0, stream>>>(S, S2, zsF);
        k_fuse2<<<dim3((unsigned)(NS / 256), 1, ZB), blk, 0, stream>>>(S2, S, zsF);
        k_softmax<<<dim3(LTOT, 1, ZB), blk, 0, stream>>>(S, mmv, attb, offout, b0, zsF, zsU);
        k_gather_rt<<<dim3((unsigned)(NRT / 256), 1, ZB), blk, 0, stream>>>(b, Rt, b0, zsU);
        // C[l,G2] = att . Rt^T : M=2304, N=2048, K=2304, plain bf16
        k_gemm_mfma<1><<<dim3(CRED / 128, LTOT / 128, ZB), blk, 0, stream>>>(
            attb, Rt, Cc, zsU, zsU, zsF, PLANE, LTOT, CRED, LTOT);
        k_output<<<dim3((CS * HS * HS) / 256, 1, ZB), blk, 0, stream>>>(Cc, yout, b0, zsF);
    }
}

// Round 4
// 645.850 us; speedup vs baseline: 7.7197x; 1.0293x over previous
//
#include <hip/hip_runtime.h>
#include <hip/hip_bf16.h>
#include <math.h>

#define IH 48
#define IW 48
#define LTOT 2304      // 48*48
#define CS 128
#define HS 96
#define KRED 1152      // 3*3*128
#define CRED 2048      // 4*4*128

typedef unsigned short u16;
typedef __attribute__((ext_vector_type(8))) short short8;
typedef __attribute__((ext_vector_type(4))) float floatx4;

#define NS    ((size_t)LTOT*LTOT)     // 5,308,416
#define PLANE ((size_t)LTOT*KRED)     // 2,654,208
#define NRT   ((size_t)CRED*LTOT)     // 4,718,592

// ---- region layout (bytes), per batch slice ----
#define OFF_APL  ((size_t)0)           // 2 bf16 planes (alias: attb)
#define OFF_BPL  ((size_t)10616832)    // 2 bf16 planes (alias: Rt)
#define OFF_S    ((size_t)21233664)    // NS fp32
#define OFF_S2   ((size_t)42467328)    // NS fp32 (alias: Cc)
#define OFF_SM   ((size_t)63700992)    // ninv + mmv
#define REGION   ((size_t)63719424)

__device__ __forceinline__ u16 f2bf(float v) {
    __hip_bfloat16 h = __float2bfloat16(v);
    return *reinterpret_cast<u16*>(&h);
}
__device__ __forceinline__ float bf2f(u16 b) {
    __hip_bfloat16 h = *reinterpret_cast<__hip_bfloat16*>(&b);
    return __bfloat162float(h);
}
__device__ __forceinline__ void split2(float v, u16& a, u16& b) {
    a = f2bf(v);
    b = f2bf(v - bf2f(a));
}

// ---------------- norm of W rows (gather-reduce) ----------------
__global__ __launch_bounds__(256) void k_wnorm(const float* __restrict__ b,
                                               float* __restrict__ ninvg,
                                               int b0, size_t zsF) {
    int bi = b0 + blockIdx.z;
    float* ninv = ninvg + (size_t)blockIdx.z * zsF;
    int l = blockIdx.x, t = threadIdx.x;
    __shared__ float red[256];
    float ss = 0.f;
    for (int G = t; G < KRED; G += 256) {
        int F = l * KRED + G;
        int p2 = F / LTOT, s = F - p2 * LTOT;
        int i = p2 / 384, j = (p2 / 128) % 3, c = p2 & 127;
        int u = s / IW + i - 1, v = s % IW + j - 1;
        if (u >= 0 && u < IH && v >= 0 && v < IW) {
            float w = b[(((size_t)bi * CS + c) * HS + 2 * u) * HS + 2 * v];
            ss += w * w;
        }
    }
    red[t] = ss; __syncthreads();
    for (int o = 128; o > 0; o >>= 1) { if (t < o) red[t] += red[t + o]; __syncthreads(); }
    if (t == 0) ninv[l] = 1.0f / fmaxf(sqrtf(red[0] + 1e-8f), 1e-4f);
}

// ---------------- gather + normalize + split W -> 2 bf16 planes ----------------
__global__ __launch_bounds__(256) void k_gather_w_split(const float* __restrict__ b,
                                                        u16* __restrict__ Ag,
                                                        const float* __restrict__ ninvg,
                                                        int b0, size_t zsU, size_t zsF) {
    int bi = b0 + blockIdx.z;
    u16* A = Ag + (size_t)blockIdx.z * zsU;
    const float* ninv = ninvg + (size_t)blockIdx.z * zsF;
    int idx = blockIdx.x * 256 + threadIdx.x;
    if (idx >= (int)PLANE) return;
    int p2 = idx / LTOT, s = idx - p2 * LTOT;
    int i = p2 / 384, j = (p2 / 128) % 3, c = p2 & 127;
    int u = s / IW + i - 1, v = s % IW + j - 1;
    float val = 0.f;
    if (u >= 0 && u < IH && v >= 0 && v < IW)
        val = b[(((size_t)bi * CS + c) * HS + 2 * u) * HS + 2 * v];
    val *= ninv[idx / KRED];
    u16 h1, h2; split2(val, h1, h2);
    A[idx] = h1; A[PLANE + idx] = h2;
}

// ---------------- gather + split Xp -> 2 bf16 planes ----------------
__global__ __launch_bounds__(256) void k_gather_x_split(const float* __restrict__ f,
                                                        u16* __restrict__ Bg,
                                                        int b0, size_t zsU) {
    int bi = b0 + blockIdx.z;
    u16* B = Bg + (size_t)blockIdx.z * zsU;
    int idx = blockIdx.x * 256 + threadIdx.x;
    if (idx >= (int)PLANE) return;
    int p = idx / KRED, G = idx - p * KRED;
    int y = p / IW, x = p % IW;
    int k1 = G / 384, k2 = (G / 128) % 3, c = G & 127;
    int u = y + k1 - 1, v = x + k2 - 1;
    float val = 0.f;
    if (u >= 0 && u < IH && v >= 0 && v < IW)
        val = f[(((size_t)bi * CS + c) * HS + 2 * u) * HS + 2 * v];
    u16 h1, h2; split2(val, h1, h2);
    B[idx] = h1; B[PLANE + idx] = h2;
}

// ---------------- mask vector ----------------
__global__ __launch_bounds__(256) void k_mm(const float* __restrict__ mask,
                                            float* __restrict__ mmvg, int b0, size_t zsF) {
    int bi = b0 + blockIdx.z;
    float* out = mmvg + (size_t)blockIdx.z * zsF;
    int q = blockIdx.x * 256 + threadIdx.x;
    if (q >= LTOT) return;
    float ssum = 0.f;
    for (int t = 0; t < 9; t++) {
        int F = q * 9 + t;
        int pm = F / LTOT, s = F % LTOT;
        int i = pm / 3, j = pm % 3;
        int u = s / IW + i - 1, v = s % IW + j - 1;
        float val = 0.f;
        if (u >= 0 && u < IH && v >= 0 && v < IW)
            val = mask[((size_t)bi * HS + 2 * u) * HS + 2 * v];
        ssum += 1.0f - val;
    }
    out[q] = (ssum / 9.0f < 0.85f) ? 1.0f : 0.0f;
}

// ---------------- gather raw patches, pre-transposed: Rt[n][k] ----------------
__global__ __launch_bounds__(256) void k_gather_rt(const float* __restrict__ b,
                                                   u16* __restrict__ Rtg,
                                                   int b0, size_t zsU) {
    int bi = b0 + blockIdx.z;
    u16* Rt = Rtg + (size_t)blockIdx.z * zsU;
    size_t idx = (size_t)blockIdx.x * 256 + threadIdx.x;
    if (idx >= NRT) return;
    int n = (int)(idx / LTOT), k = (int)(idx - (size_t)n * LTOT);
    size_t F = (size_t)k * CRED + n;
    int pr = (int)(F / LTOT);
    int s = (int)(F - (size_t)pr * LTOT);
    int i = pr / 512, j = (pr / 128) & 3, c = pr & 127;
    int Y0 = 2 * (s / IW) + i - 1, X0 = 2 * (s % IW) + j - 1;
    float val = 0.f;
    if (Y0 >= 0 && Y0 < HS && X0 >= 0 && X0 < HS)
        val = b[(((size_t)bi * CS + c) * HS + Y0) * HS + X0];
    Rt[idx] = f2bf(val);
}

// ---------------- pipelined MFMA GEMM (NT) ----------------
// 128x128 tile, 4 waves (2x2), BK=32, 4 LDS buffers (64KB), global_load_lds direct,
// counted vmcnt (never 0 in steady state), raw barriers, setprio around MFMA.
// LDS: buffer bb: A[128][32] at bb*8192, B[128][32] at bb*8192+4096 (u16).
// Swizzle: 16B-slot phys = slot ^ ((row>>1)&3), applied on global SOURCE address
// (LDS dest stays linear for gload_lds) and on ds_read (both-sides, rule #21).
// MODE=1: split-2 bf16 as one NT GEMM with K'=3456: tiles 0-35 hi*hi,
//         36-71 lo*hi, 72-107 hi*lo.  MODE=0: plain bf16.
template <int MODE>
__device__ __forceinline__ void tile_off(int t, size_t& oA, size_t& oB) {
    if constexpr (MODE == 1) {
        int tm = t, pA = 0, pB = 0;
        if (t >= 72)      { tm = t - 72; pB = 1; }
        else if (t >= 36) { tm = t - 36; pA = 1; }
        oA = (size_t)pA * PLANE + (size_t)tm * 32;
        oB = (size_t)pB * PLANE + (size_t)tm * 32;
    } else {
        oA = (size_t)t * 32; oB = oA;
    }
}

template <int MODE>
__device__ __forceinline__ void stage_tile(const u16* __restrict__ A,
                                           const u16* __restrict__ B,
                                           u16* lds, int t, int bb,
                                           int bm, int bn, int sA, int sB,
                                           int lane, int wave) {
    size_t oA, oB; tile_off<MODE>(t, oA, oB);
    int r16 = lane >> 2;
    int sl0 = lane & 3;
#pragma unroll
    for (int e = 0; e < 2; ++e) {
        int rbase = wave * 32 + e * 16;
        int row = rbase + r16;
        int sl = (sl0 ^ ((row >> 1) & 3)) << 3;
        const u16* gA = A + oA + (size_t)(bm + row) * sA + sl;
        const u16* gB = B + oB + (size_t)(bn + row) * sB + sl;
        u16* lA = lds + bb * 8192 + rbase * 32;   // wave-uniform base
        u16* lB = lA + 4096;
        __builtin_amdgcn_global_load_lds((const __attribute__((address_space(1))) void*)gA,
                                         (__attribute__((address_space(3))) void*)lA, 16, 0, 0);
        __builtin_amdgcn_global_load_lds((const __attribute__((address_space(1))) void*)gB,
                                         (__attribute__((address_space(3))) void*)lB, 16, 0, 0);
    }
}

template <int MODE>
__global__ __launch_bounds__(256, 2) void k_gemm_pipe(const u16* __restrict__ Ag,
                                                      const u16* __restrict__ Bg,
                                                      float* __restrict__ Cg,
                                                      size_t zsA, size_t zsB, size_t zsC,
                                                      int gx, int gy, int sA, int sB,
                                                      int N, int NT) {
    __shared__ u16 lds[32768];
    // bijective XCD swizzle (m204)
    unsigned nwg = gridDim.x, orig = blockIdx.x;
    unsigned q = nwg >> 3, rr = nwg & 7, xcd = orig & 7, lid = orig >> 3;
    unsigned wg = (xcd < rr ? xcd * (q + 1) : rr * (q + 1) + (xcd - rr) * q) + lid;
    unsigned per_z = (unsigned)(gx * gy);
    int z = wg / per_z;
    int r2 = wg % per_z;
    int by = r2 / gx, bx = r2 % gx;
    const u16* A = Ag + (size_t)z * zsA;
    const u16* B = Bg + (size_t)z * zsB;
    float* C = Cg + (size_t)z * zsC;
    const int bm = by * 128, bn = bx * 128;
    const int tid = threadIdx.x, lane = tid & 63, wave = tid >> 6;
    const int wr = (wave >> 1) * 64, wc = (wave & 1) * 64;
    const int lrow = lane & 15, lq = lane >> 4;

    floatx4 acc[4][4];
#pragma unroll
    for (int i = 0; i < 4; i++)
#pragma unroll
        for (int j = 0; j < 4; j++) acc[i][j] = (floatx4){0.f, 0.f, 0.f, 0.f};

    stage_tile<MODE>(A, B, lds, 0, 0, bm, bn, sA, sB, lane, wave);
    stage_tile<MODE>(A, B, lds, 1, 1, bm, bn, sA, sB, lane, wave);
    stage_tile<MODE>(A, B, lds, 2, 2, bm, bn, sA, sB, lane, wave);

    for (int t = 0; t < NT; ++t) {
        int bb = t & 3;
        if (t + 3 < NT)
            stage_tile<MODE>(A, B, lds, t + 3, (t + 3) & 3, bm, bn, sA, sB, lane, wave);
        int rem = NT - 1 - t;
        if (rem >= 3)      asm volatile("s_waitcnt vmcnt(12)" ::: "memory");
        else if (rem == 2) asm volatile("s_waitcnt vmcnt(8)" ::: "memory");
        else if (rem == 1) asm volatile("s_waitcnt vmcnt(4)" ::: "memory");
        else               asm volatile("s_waitcnt vmcnt(0)" ::: "memory");
        asm volatile("s_barrier" ::: "memory");

        short8 af[4], bf[4];
#pragma unroll
        for (int mi = 0; mi < 4; ++mi) {
            int row = wr + mi * 16 + lrow;
            af[mi] = *(const short8*)&lds[bb * 8192 + row * 32 + ((lq ^ ((row >> 1) & 3)) << 3)];
        }
#pragma unroll
        for (int ni = 0; ni < 4; ++ni) {
            int row = wc + ni * 16 + lrow;
            bf[ni] = *(const short8*)&lds[bb * 8192 + 4096 + row * 32 + ((lq ^ ((row >> 1) & 3)) << 3)];
        }
        __builtin_amdgcn_s_setprio(1);
#pragma unroll
        for (int ni = 0; ni < 4; ++ni)
#pragma unroll
            for (int mi = 0; mi < 4; ++mi)
                acc[mi][ni] = __builtin_amdgcn_mfma_f32_16x16x32_bf16(af[mi], bf[ni], acc[mi][ni], 0, 0, 0);
        __builtin_amdgcn_s_setprio(0);
        asm volatile("s_barrier" ::: "memory");
    }

    const int r0 = bm + wr + (lane >> 4) * 4;
    const int c0 = bn + wc + (lane & 15);
#pragma unroll
    for (int mi = 0; mi < 4; ++mi)
#pragma unroll
        for (int ni = 0; ni < 4; ++ni)
#pragma unroll
            for (int j = 0; j < 4; ++j)
                C[(size_t)(r0 + mi * 16 + j) * N + (c0 + ni * 16)] = acc[mi][ni][j];
}

// ---------------- fused fuse1+fuse2 (9-point gather, exact add tree) ----------------
__device__ __forceinline__ int permi(int a) { return (a % 48) * 48 + a / 48; }

__device__ __forceinline__ float f1_at(const float* __restrict__ S, int a, int b) {
    float s = S[(size_t)a * LTOT + b];
    if (a >= 1 && b >= 1) s += S[(size_t)(a - 1) * LTOT + (b - 1)];
    if (a < LTOT - 1 && b < LTOT - 1) s += S[(size_t)(a + 1) * LTOT + (b + 1)];
    return s;
}

__global__ __launch_bounds__(256) void k_fuse12(const float* __restrict__ Sg,
                                                float* __restrict__ Dg, size_t zsF) {
    const float* S = Sg + (size_t)blockIdx.z * zsF;
    float* D = Dg + (size_t)blockIdx.z * zsF;
    size_t idx = (size_t)blockIdx.x * 256 + threadIdx.x;
    if (idx >= NS) return;
    int A = (int)(idx / LTOT), B = (int)(idx % LTOT);
    int At = permi(A), Bt = permi(B);
    float s = f1_at(S, A, B);
    if (At >= 1 && Bt >= 1)
        s += f1_at(S, permi(At - 1), permi(Bt - 1));
    if (At < LTOT - 1 && Bt < LTOT - 1)
        s += f1_at(S, permi(At + 1), permi(Bt + 1));
    D[idx] = s;
}

// ---------------- softmax + argmax + offsets (register-resident row) ----------------
__global__ __launch_bounds__(256) void k_softmax(const float* __restrict__ Sg,
                                                 const float* __restrict__ mmg,
                                                 u16* __restrict__ attbg,
                                                 float* __restrict__ offout,
                                                 int b0, size_t zsF, size_t zsU) {
    int bi = b0 + blockIdx.z;
    const float* S = Sg + (size_t)blockIdx.z * zsF;
    const float* mm = mmg + (size_t)blockIdx.z * zsF;
    u16* attb = attbg + (size_t)blockIdx.z * zsU;
    int l = blockIdx.x, t = threadIdx.x;
    __shared__ float red[256];
    __shared__ int redi[256];
    const float* row = S + (size_t)l * LTOT;
    u16* arow = attb + (size_t)l * LTOT;

    float v[9], m9[9];
#pragma unroll
    for (int i = 0; i < 9; ++i) {
        int p = t + 256 * i;
        m9[i] = mm[p];
        v[i] = row[p] * m9[i] * 10.0f;
    }
    float mx = -1e30f;
#pragma unroll
    for (int i = 0; i < 9; ++i) mx = fmaxf(mx, v[i]);
    red[t] = mx; __syncthreads();
    for (int o = 128; o > 0; o >>= 1) { if (t < o) red[t] = fmaxf(red[t], red[t + o]); __syncthreads(); }
    mx = red[0]; __syncthreads();
    float sm = 0.f;
#pragma unroll
    for (int i = 0; i < 9; ++i) sm += expf(v[i] - mx);
    red[t] = sm; __syncthreads();
    for (int o = 128; o > 0; o >>= 1) { if (t < o) red[t] += red[t + o]; __syncthreads(); }
    float Z = red[0]; __syncthreads();
    float bv = -1.0f; int bidx2 = 0;
#pragma unroll
    for (int i = 0; i < 9; ++i) {
        int p = t + 256 * i;
        float e = expf(v[i] - mx);
        float a = (e / Z) * m9[i];
        arow[p] = f2bf(a);
        if (a > bv) { bv = a; bidx2 = p; }
    }
    red[t] = bv; redi[t] = bidx2; __syncthreads();
    for (int o = 128; o > 0; o >>= 1) {
        if (t < o) {
            if (red[t + o] > red[t] || (red[t + o] == red[t] && redi[t + o] < redi[t])) {
                red[t] = red[t + o]; redi[t] = redi[t + o];
            }
        }
        __syncthreads();
    }
    if (t == 0) {
        int off = redi[0];
        int ly = l / IW, lx = l % IW;
        offout[((size_t)bi * 2 + 0) * LTOT + l] = (float)(off / 96 - ly);
        offout[((size_t)bi * 2 + 1) * LTOT + l] = (float)(off % 96 - lx);
    }
}

// ---------------- transposed-conv reduction ----------------
__global__ __launch_bounds__(256) void k_output(const float* __restrict__ Cg,
                                                float* __restrict__ yout,
                                                int b0, size_t zsF) {
    int bi = b0 + blockIdx.z;
    const float* C = Cg + (size_t)blockIdx.z * zsF;
    int idx = blockIdx.x * 256 + threadIdx.x;
    if (idx >= CS * HS * HS) return;
    int c = idx / (HS * HS), rem = idx % (HS * HS);
    int Y = rem / HS, X = rem % HS;
    float s = 0.f;
    int pu = (Y + 1) & 1, pv = (X + 1) & 1;
    for (int a = 0; a < 2; a++) {
        int u = pu + 2 * a;
        int ly2 = Y + 1 - u;
        if (ly2 < 0) continue;
        int ly = ly2 >> 1;
        if (ly >= IH) continue;
        for (int bb = 0; bb < 2; bb++) {
            int v = pv + 2 * bb;
            int lx2 = X + 1 - v;
            if (lx2 < 0) continue;
            int lx = lx2 >> 1;
            if (lx >= IW) continue;
            s += C[(size_t)(ly * IW + lx) * CRED + u * 512 + v * 128 + c];
        }
    }
    yout[(size_t)bi * CS * HS * HS + idx] = s * 0.25f;
}

// ---------------- launch ----------------
extern "C" void kernel_launch(void* const* d_in, const int* in_sizes, int n_in,
                              void* d_out, int out_size, void* d_ws, size_t ws_size,
                              hipStream_t stream) {
    const float* f = (const float*)d_in[0];
    const float* b = (const float*)d_in[1];
    const float* mask = (const float*)d_in[2];
    float* yout = (float*)d_out;
    float* offout = yout + (size_t)4 * CS * HS * HS;

    int ZB, nloop;
    if (ws_size >= 4 * REGION)      { ZB = 4; nloop = 1; }
    else if (ws_size >= 2 * REGION) { ZB = 2; nloop = 2; }
    else                            { ZB = 1; nloop = 4; }

    char* base = (char*)d_ws;
    u16*   Apl  = (u16*)(base + OFF_APL);
    u16*   Bpl  = (u16*)(base + OFF_BPL);
    float* S    = (float*)(base + OFF_S);
    float* S2   = (float*)(base + OFF_S2);
    float* ninv = (float*)(base + OFF_SM);
    float* mmv  = ninv + LTOT;
    u16*   attb = Apl;   // alias (A planes dead after gemm1)
    u16*   Rt   = Bpl;   // alias (B planes dead after gemm1)
    float* Cc   = S2;    // alias (S2 dead after softmax reads it)

    const size_t zsU = REGION / 2;   // per-z stride in u16 elements
    const size_t zsF = REGION / 4;   // per-z stride in float elements

    dim3 blk(256, 1, 1);

    for (int it = 0; it < nloop; ++it) {
        int b0 = it * ZB;
        k_wnorm<<<dim3(LTOT, 1, ZB), blk, 0, stream>>>(b, ninv, b0, zsF);
        k_gather_w_split<<<dim3((unsigned)(PLANE / 256), 1, ZB), blk, 0, stream>>>(b, Apl, ninv, b0, zsU, zsF);
        k_gather_x_split<<<dim3((unsigned)(PLANE / 256), 1, ZB), blk, 0, stream>>>(f, Bpl, b0, zsU);
        k_mm<<<dim3((LTOT + 255) / 256, 1, ZB), blk, 0, stream>>>(mask, mmv, b0, zsF);
        // GEMM1: S[l,p], M=N=2304, K'=3456 (split-2 via plane-remapped K), NT=108
        k_gemm_pipe<1><<<dim3(18 * 18 * ZB), blk, 0, stream>>>(
            Apl, Bpl, S, zsU, zsU, zsF, 18, 18, KRED, KRED, LTOT, 108);
        k_fuse12<<<dim3((unsigned)(NS / 256), 1, ZB), blk, 0, stream>>>(S, S2, zsF);
        k_softmax<<<dim3(LTOT, 1, ZB), blk, 0, stream>>>(S2, mmv, attb, offout, b0, zsF, zsU);
        k_gather_rt<<<dim3((unsigned)(NRT / 256), 1, ZB), blk, 0, stream>>>(b, Rt, b0, zsU);
        // GEMM2: C[l,G2] = att . Rt^T, M=2304, N=2048, K=2304, NT=72
        k_gemm_pipe<0><<<dim3(16 * 18 * ZB), blk, 0, stream>>>(
            attb, Rt, Cc, zsU, zsU, zsF, 16, 18, LTOT, LTOT, CRED, 72);
        k_output<<<dim3((CS * HS * HS) / 256, 1, ZB), blk, 0, stream>>>(Cc, yout, b0, zsF);
    }
}

// Round 5
// 610.448 us; speedup vs baseline: 8.1674x; 1.0580x over previous
//
#include <hip/hip_runtime.h>
#include <hip/hip_bf16.h>
#include <math.h>

#define IH 48
#define IW 48
#define LTOT 2304      // 48*48
#define CS 128
#define HS 96
#define KRED 1152      // 3*3*128
#define CRED 2048      // 4*4*128

typedef unsigned short u16;
typedef __attribute__((ext_vector_type(8))) short short8;
typedef __attribute__((ext_vector_type(8))) unsigned short ushort8;
typedef __attribute__((ext_vector_type(4))) float floatx4;

#define NS    ((size_t)LTOT*LTOT)     // 5,308,416
#define PLANE ((size_t)LTOT*KRED)     // 2,654,208
#define NRT   ((size_t)CRED*LTOT)     // 4,718,592

// ---- region layout (bytes), per batch slice ----
#define OFF_APL  ((size_t)0)           // 2 bf16 planes (alias: attb)
#define OFF_BPL  ((size_t)10616832)    // 2 bf16 planes (alias: Rt)
#define OFF_S    ((size_t)21233664)    // NS fp32 (raw scores)
#define OFF_S2   ((size_t)42467328)    // Cc (gemm2 out, 18.9MB)
#define OFF_SM   ((size_t)63700992)    // ninv + mmv
#define REGION   ((size_t)63719424)

__device__ __forceinline__ u16 f2bf(float v) {
    __hip_bfloat16 h = __float2bfloat16(v);
    return *reinterpret_cast<u16*>(&h);
}
__device__ __forceinline__ float bf2f(u16 b) {
    __hip_bfloat16 h = *reinterpret_cast<__hip_bfloat16*>(&b);
    return __bfloat162float(h);
}
__device__ __forceinline__ void split2(float v, u16& a, u16& b) {
    a = f2bf(v);
    b = f2bf(v - bf2f(a));
}

// ---------------- norm of W rows (gather-reduce) ----------------
__global__ __launch_bounds__(256) void k_wnorm(const float* __restrict__ b,
                                               float* __restrict__ ninvg,
                                               int b0, size_t zsF) {
    int bi = b0 + blockIdx.z;
    float* ninv = ninvg + (size_t)blockIdx.z * zsF;
    int l = blockIdx.x, t = threadIdx.x;
    __shared__ float red[256];
    float ss = 0.f;
    for (int G = t; G < KRED; G += 256) {
        int F = l * KRED + G;
        int p2 = F / LTOT, s = F - p2 * LTOT;
        int i = p2 / 384, j = (p2 / 128) % 3, c = p2 & 127;
        int u = s / IW + i - 1, v = s % IW + j - 1;
        if (u >= 0 && u < IH && v >= 0 && v < IW) {
            float w = b[(((size_t)bi * CS + c) * HS + 2 * u) * HS + 2 * v];
            ss += w * w;
        }
    }
    red[t] = ss; __syncthreads();
    for (int o = 128; o > 0; o >>= 1) { if (t < o) red[t] += red[t + o]; __syncthreads(); }
    if (t == 0) ninv[l] = 1.0f / fmaxf(sqrtf(red[0] + 1e-8f), 1e-4f);
}

// ---------------- merged gather: W (normalized, split) and Xp (split) ----------------
__global__ __launch_bounds__(256) void k_gather_ab(const float* __restrict__ b,
                                                   const float* __restrict__ f,
                                                   u16* __restrict__ Ag,
                                                   u16* __restrict__ Bg,
                                                   const float* __restrict__ ninvg,
                                                   int b0, size_t zsU, size_t zsF) {
    const unsigned half = (unsigned)(PLANE / 256);
    int bi = b0 + blockIdx.z;
    if (blockIdx.x < half) {
        // W side
        u16* A = Ag + (size_t)blockIdx.z * zsU;
        const float* ninv = ninvg + (size_t)blockIdx.z * zsF;
        int idx = blockIdx.x * 256 + threadIdx.x;
        int p2 = idx / LTOT, s = idx - p2 * LTOT;
        int i = p2 / 384, j = (p2 / 128) % 3, c = p2 & 127;
        int u = s / IW + i - 1, v = s % IW + j - 1;
        float val = 0.f;
        if (u >= 0 && u < IH && v >= 0 && v < IW)
            val = b[(((size_t)bi * CS + c) * HS + 2 * u) * HS + 2 * v];
        val *= ninv[idx / KRED];
        u16 h1, h2; split2(val, h1, h2);
        A[idx] = h1; A[PLANE + idx] = h2;
    } else {
        // Xp side
        u16* B = Bg + (size_t)blockIdx.z * zsU;
        int idx = (blockIdx.x - half) * 256 + threadIdx.x;
        int p = idx / KRED, G = idx - p * KRED;
        int y = p / IW, x = p % IW;
        int k1 = G / 384, k2 = (G / 128) % 3, c = G & 127;
        int u = y + k1 - 1, v = x + k2 - 1;
        float val = 0.f;
        if (u >= 0 && u < IH && v >= 0 && v < IW)
            val = f[(((size_t)bi * CS + c) * HS + 2 * u) * HS + 2 * v];
        u16 h1, h2; split2(val, h1, h2);
        B[idx] = h1; B[PLANE + idx] = h2;
    }
}

// ---------------- mask vector ----------------
__global__ __launch_bounds__(256) void k_mm(const float* __restrict__ mask,
                                            float* __restrict__ mmvg, int b0, size_t zsF) {
    int bi = b0 + blockIdx.z;
    float* out = mmvg + (size_t)blockIdx.z * zsF;
    int q = blockIdx.x * 256 + threadIdx.x;
    if (q >= LTOT) return;
    float ssum = 0.f;
    for (int t = 0; t < 9; t++) {
        int F = q * 9 + t;
        int pm = F / LTOT, s = F % LTOT;
        int i = pm / 3, j = pm % 3;
        int u = s / IW + i - 1, v = s % IW + j - 1;
        float val = 0.f;
        if (u >= 0 && u < IH && v >= 0 && v < IW)
            val = mask[((size_t)bi * HS + 2 * u) * HS + 2 * v];
        ssum += 1.0f - val;
    }
    out[q] = (ssum / 9.0f < 0.85f) ? 1.0f : 0.0f;
}

// ---------------- gather raw patches, pre-transposed: Rt[n][k] ----------------
__global__ __launch_bounds__(256) void k_gather_rt(const float* __restrict__ b,
                                                   u16* __restrict__ Rtg,
                                                   int b0, size_t zsU) {
    int bi = b0 + blockIdx.z;
    u16* Rt = Rtg + (size_t)blockIdx.z * zsU;
    size_t idx = (size_t)blockIdx.x * 256 + threadIdx.x;
    if (idx >= NRT) return;
    int n = (int)(idx / LTOT), k = (int)(idx - (size_t)n * LTOT);
    size_t F = (size_t)k * CRED + n;
    int pr = (int)(F / LTOT);
    int s = (int)(F - (size_t)pr * LTOT);
    int i = pr / 512, j = (pr / 128) & 3, c = pr & 127;
    int Y0 = 2 * (s / IW) + i - 1, X0 = 2 * (s % IW) + j - 1;
    float val = 0.f;
    if (Y0 >= 0 && Y0 < HS && X0 >= 0 && X0 < HS)
        val = b[(((size_t)bi * CS + c) * HS + Y0) * HS + X0];
    Rt[idx] = f2bf(val);
}

// ---------------- MFMA GEMM (NT): C[m,n] = sum_k A[m,k]*B[n,k] ----------------
// Round-3 proven structure: 128x128 tile, BK=64, 4 waves (2x2), XOR-8 LDS swizzle
// (0 bank conflicts measured), reg-staged, 2-barrier loop.
// NP=2: 3-product split-2 (lo*hi + hi*lo + hi*hi, small-first). NP=1: plain bf16.
template <int NP>
__global__ __launch_bounds__(256) void k_gemm_mfma(const u16* __restrict__ Ag,
                                                   const u16* __restrict__ Bg,
                                                   float* __restrict__ Cg,
                                                   size_t zsA, size_t zsB, size_t zsC,
                                                   size_t planeStride,
                                                   int M, int N, int K) {
    const u16* A = Ag + (size_t)blockIdx.z * zsA;
    const u16* B = Bg + (size_t)blockIdx.z * zsB;
    float* C = Cg + (size_t)blockIdx.z * zsC;
    __shared__ u16 lds[NP * 8192 * 2];
    u16* As = lds;
    u16* Bs = lds + NP * 8192;
    const int tid = threadIdx.x;
    const int lane = tid & 63;
    const int wave = tid >> 6;
    const int wr = (wave >> 1) * 64, wc = (wave & 1) * 64;
    const int lrow = lane & 15, lq = lane >> 4;
    const int bm = blockIdx.y * 128, bn = blockIdx.x * 128;

    floatx4 acc[4][4];
#pragma unroll
    for (int i = 0; i < 4; i++)
#pragma unroll
        for (int j = 0; j < 4; j++) acc[i][j] = (floatx4){0.f, 0.f, 0.f, 0.f};

    for (int kt = 0; kt < K; kt += 64) {
        ushort8 stA[NP * 4], stB[NP * 4];
#pragma unroll
        for (int e = 0; e < NP * 4; ++e) {
            int g = e * 256 + tid;
            int p = g >> 10;             // plane
            int gg = g & 1023;           // chunk within plane: 128 rows x 8 slots
            int row = gg >> 3, slot = gg & 7;
            stA[e] = *(const ushort8*)(A + (size_t)p * planeStride + (size_t)(bm + row) * K + kt + slot * 8);
            stB[e] = *(const ushort8*)(B + (size_t)p * planeStride + (size_t)(bn + row) * K + kt + slot * 8);
        }
        __syncthreads();   // prior compute finished reading LDS
#pragma unroll
        for (int e = 0; e < NP * 4; ++e) {
            int g = e * 256 + tid;
            int p = g >> 10;
            int gg = g & 1023;
            int row = gg >> 3, slot = gg & 7;
            int dst = p * 8192 + row * 64 + ((slot ^ (row & 7)) << 3);
            *(ushort8*)&As[dst] = stA[e];
            *(ushort8*)&Bs[dst] = stB[e];
        }
        __syncthreads();

#pragma unroll
        for (int ks = 0; ks < 2; ++ks) {
            short8 af[NP][4];
#pragma unroll
            for (int p = 0; p < NP; ++p)
#pragma unroll
                for (int mi = 0; mi < 4; ++mi) {
                    int row = wr + mi * 16 + lrow;
                    af[p][mi] = *(const short8*)&As[p * 8192 + row * 64 + ((((ks << 2) | lq) ^ (row & 7)) << 3)];
                }
#pragma unroll
            for (int ni = 0; ni < 4; ++ni) {
                short8 bfr[NP];
                int rowb = wc + ni * 16 + lrow;
                int bslot = ((((ks << 2) | lq) ^ (rowb & 7)) << 3);
#pragma unroll
                for (int p = 0; p < NP; ++p)
                    bfr[p] = *(const short8*)&Bs[p * 8192 + rowb * 64 + bslot];
#pragma unroll
                for (int mi = 0; mi < 4; ++mi) {
                    if constexpr (NP == 1) {
                        acc[mi][ni] = __builtin_amdgcn_mfma_f32_16x16x32_bf16(af[0][mi], bfr[0], acc[mi][ni], 0, 0, 0);
                    } else {
                        // small-first: lo*hi, hi*lo, hi*hi
                        acc[mi][ni] = __builtin_amdgcn_mfma_f32_16x16x32_bf16(af[1][mi], bfr[0], acc[mi][ni], 0, 0, 0);
                        acc[mi][ni] = __builtin_amdgcn_mfma_f32_16x16x32_bf16(af[0][mi], bfr[1], acc[mi][ni], 0, 0, 0);
                        acc[mi][ni] = __builtin_amdgcn_mfma_f32_16x16x32_bf16(af[0][mi], bfr[0], acc[mi][ni], 0, 0, 0);
                    }
                }
            }
        }
    }

    const int r0 = bm + wr + (lane >> 4) * 4;
    const int c0 = bn + wc + (lane & 15);
#pragma unroll
    for (int mi = 0; mi < 4; ++mi)
#pragma unroll
        for (int ni = 0; ni < 4; ++ni)
#pragma unroll
            for (int j = 0; j < 4; ++j)
                C[(size_t)(r0 + mi * 16 + j) * N + (c0 + ni * 16)] = acc[mi][ni][j];
}

// ---------------- fused fuse1+fuse2+softmax+argmax ----------------
__device__ __forceinline__ int permi(int a) { return (a % 48) * 48 + a / 48; }

__device__ __forceinline__ float f1_at(const float* __restrict__ S, int a, int b) {
    float s = S[(size_t)a * LTOT + b];
    if (a >= 1 && b >= 1) s += S[(size_t)(a - 1) * LTOT + (b - 1)];
    if (a < LTOT - 1 && b < LTOT - 1) s += S[(size_t)(a + 1) * LTOT + (b + 1)];
    return s;
}

__global__ __launch_bounds__(256) void k_fusesoftmax(const float* __restrict__ Sg,
                                                     const float* __restrict__ mmg,
                                                     u16* __restrict__ attbg,
                                                     float* __restrict__ offout,
                                                     int b0, size_t zsF, size_t zsU) {
    int bi = b0 + blockIdx.z;
    const float* S = Sg + (size_t)blockIdx.z * zsF;
    const float* mm = mmg + (size_t)blockIdx.z * zsF;
    u16* attb = attbg + (size_t)blockIdx.z * zsU;
    int l = blockIdx.x, t = threadIdx.x;
    __shared__ float red[256];
    __shared__ int redi[256];
    u16* arow = attb + (size_t)l * LTOT;

    const int At = permi(l);
    const int rm = (At >= 1) ? permi(At - 1) : -1;          // wave-uniform rows
    const int rp = (At < LTOT - 1) ? permi(At + 1) : -1;

    float v[9], m9[9];
#pragma unroll
    for (int i = 0; i < 9; ++i) {
        int p = t + 256 * i;
        float d = f1_at(S, l, p);
        int Bt = permi(p);
        if (rm >= 0 && Bt >= 1)        d += f1_at(S, rm, permi(Bt - 1));
        if (rp >= 0 && Bt < LTOT - 1)  d += f1_at(S, rp, permi(Bt + 1));
        m9[i] = mm[p];
        v[i] = d * m9[i] * 10.0f;
    }
    float mx = -1e30f;
#pragma unroll
    for (int i = 0; i < 9; ++i) mx = fmaxf(mx, v[i]);
    red[t] = mx; __syncthreads();
    for (int o = 128; o > 0; o >>= 1) { if (t < o) red[t] = fmaxf(red[t], red[t + o]); __syncthreads(); }
    mx = red[0]; __syncthreads();
    float sm = 0.f;
#pragma unroll
    for (int i = 0; i < 9; ++i) sm += expf(v[i] - mx);
    red[t] = sm; __syncthreads();
    for (int o = 128; o > 0; o >>= 1) { if (t < o) red[t] += red[t + o]; __syncthreads(); }
    float Z = red[0]; __syncthreads();
    float bv = -1.0f; int bidx2 = 0;
#pragma unroll
    for (int i = 0; i < 9; ++i) {
        int p = t + 256 * i;
        float e = expf(v[i] - mx);
        float a = (e / Z) * m9[i];
        arow[p] = f2bf(a);
        if (a > bv) { bv = a; bidx2 = p; }
    }
    red[t] = bv; redi[t] = bidx2; __syncthreads();
    for (int o = 128; o > 0; o >>= 1) {
        if (t < o) {
            if (red[t + o] > red[t] || (red[t + o] == red[t] && redi[t + o] < redi[t])) {
                red[t] = red[t + o]; redi[t] = redi[t + o];
            }
        }
        __syncthreads();
    }
    if (t == 0) {
        int off = redi[0];
        int ly = l / IW, lx = l % IW;
        offout[((size_t)bi * 2 + 0) * LTOT + l] = (float)(off / 96 - ly);
        offout[((size_t)bi * 2 + 1) * LTOT + l] = (float)(off % 96 - lx);
    }
}

// ---------------- transposed-conv reduction ----------------
__global__ __launch_bounds__(256) void k_output(const float* __restrict__ Cg,
                                                float* __restrict__ yout,
                                                int b0, size_t zsF) {
    int bi = b0 + blockIdx.z;
    const float* C = Cg + (size_t)blockIdx.z * zsF;
    int idx = blockIdx.x * 256 + threadIdx.x;
    if (idx >= CS * HS * HS) return;
    int c = idx / (HS * HS), rem = idx % (HS * HS);
    int Y = rem / HS, X = rem % HS;
    float s = 0.f;
    int pu = (Y + 1) & 1, pv = (X + 1) & 1;
    for (int a = 0; a < 2; a++) {
        int u = pu + 2 * a;
        int ly2 = Y + 1 - u;
        if (ly2 < 0) continue;
        int ly = ly2 >> 1;
        if (ly >= IH) continue;
        for (int bb = 0; bb < 2; bb++) {
            int v = pv + 2 * bb;
            int lx2 = X + 1 - v;
            if (lx2 < 0) continue;
            int lx = lx2 >> 1;
            if (lx >= IW) continue;
            s += C[(size_t)(ly * IW + lx) * CRED + u * 512 + v * 128 + c];
        }
    }
    yout[(size_t)bi * CS * HS * HS + idx] = s * 0.25f;
}

// ---------------- launch ----------------
extern "C" void kernel_launch(void* const* d_in, const int* in_sizes, int n_in,
                              void* d_out, int out_size, void* d_ws, size_t ws_size,
                              hipStream_t stream) {
    const float* f = (const float*)d_in[0];
    const float* b = (const float*)d_in[1];
    const float* mask = (const float*)d_in[2];
    float* yout = (float*)d_out;
    float* offout = yout + (size_t)4 * CS * HS * HS;

    int ZB, nloop;
    if (ws_size >= 4 * REGION)      { ZB = 4; nloop = 1; }
    else if (ws_size >= 2 * REGION) { ZB = 2; nloop = 2; }
    else                            { ZB = 1; nloop = 4; }

    char* base = (char*)d_ws;
    u16*   Apl  = (u16*)(base + OFF_APL);
    u16*   Bpl  = (u16*)(base + OFF_BPL);
    float* S    = (float*)(base + OFF_S);
    float* Cc   = (float*)(base + OFF_S2);
    float* ninv = (float*)(base + OFF_SM);
    float* mmv  = ninv + LTOT;
    u16*   attb = Apl;   // alias (A planes dead after gemm1)
    u16*   Rt   = Bpl;   // alias (B planes dead after gemm1)

    const size_t zsU = REGION / 2;   // per-z stride in u16 elements
    const size_t zsF = REGION / 4;   // per-z stride in float elements

    dim3 blk(256, 1, 1);
    const unsigned ghalf = (unsigned)(PLANE / 256);

    for (int it = 0; it < nloop; ++it) {
        int b0 = it * ZB;
        k_wnorm<<<dim3(LTOT, 1, ZB), blk, 0, stream>>>(b, ninv, b0, zsF);
        k_gather_ab<<<dim3(2 * ghalf, 1, ZB), blk, 0, stream>>>(b, f, Apl, Bpl, ninv, b0, zsU, zsF);
        k_mm<<<dim3((LTOT + 255) / 256, 1, ZB), blk, 0, stream>>>(mask, mmv, b0, zsF);
        // GEMM1: S[l,p] = Wn . Xp^T : M=N=2304, K=1152, split-2, 3 products
        k_gemm_mfma<2><<<dim3(LTOT / 128, LTOT / 128, ZB), blk, 0, stream>>>(
            Apl, Bpl, S, zsU, zsU, zsF, PLANE, LTOT, LTOT, KRED);
        // fused fuse1+fuse2+softmax+argmax
        k_fusesoftmax<<<dim3(LTOT, 1, ZB), blk, 0, stream>>>(S, mmv, attb, offout, b0, zsF, zsU);
        k_gather_rt<<<dim3((unsigned)(NRT / 256), 1, ZB), blk, 0, stream>>>(b, Rt, b0, zsU);
        // GEMM2: C[l,G2] = att . Rt^T : M=2304, N=2048, K=2304, plain bf16
        k_gemm_mfma<1><<<dim3(CRED / 128, LTOT / 128, ZB), blk, 0, stream>>>(
            attb, Rt, Cc, zsU, zsU, zsF, PLANE, LTOT, CRED, LTOT);
        k_output<<<dim3((CS * HS * HS) / 256, 1, ZB), blk, 0, stream>>>(Cc, yout, b0, zsF);
    }
}